// Round 1
// baseline (13248.720 us; speedup 1.0000x reference)
//
#include <hip/hip_runtime.h>
#include <math.h>

#define TAU 3.0f
#define NB 256          // batch
#define DD 1024         // embedding dim
#define KSEL 3

// ---------------- inverse L2 norms (clamped) ----------------
__global__ void invnorm_kernel(const float* __restrict__ x, float* __restrict__ inv) {
    int row = blockIdx.x;
    const float* p = x + (size_t)row * DD;
    int lane = threadIdx.x; // 64
    float s = 0.f;
#pragma unroll
    for (int i = 0; i < 4; ++i) {
        float4 v = *reinterpret_cast<const float4*>(p + (size_t)(i * 64 + lane) * 4);
        s = fmaf(v.x, v.x, fmaf(v.y, v.y, fmaf(v.z, v.z, fmaf(v.w, v.w, s))));
    }
#pragma unroll
    for (int off = 32; off; off >>= 1) s += __shfl_down(s, off);
    if (lane == 0) inv[row] = 1.0f / fmaxf(sqrtf(s), 1e-8f);
}

// ---------------- fused pairwise block-sim ----------------
// One block per task t. n = t/P, col-index = bsel ? bsel[t] : t%P.
// out[t] = sum_l max_r ( (A[n,r,:]*invA) . (B[b,l,:]*invB) )
template<int R, int L>
__global__ __launch_bounds__(256) void blocksim_kernel(
    const float* __restrict__ A, const float* __restrict__ invA,
    const float* __restrict__ Bm, const float* __restrict__ invB,
    const int* __restrict__ bsel, int P, float* __restrict__ out)
{
    constexpr int CH = 64, CHP = 68;               // +4 pad: keeps 16B align, breaks bank stride
    constexpr int TI = (R + 15) / 16, TJ = (L + 15) / 16;
    __shared__ __align__(16) float As[R][CHP];
    __shared__ __align__(16) float Bs[L][CHP];
    __shared__ float colmax[L];

    int t = blockIdx.x;
    int n = t / P;
    int pk = t - n * P;
    int brow = bsel ? bsel[t] : pk;

    const float* Ab = A + (size_t)n * R * DD;
    const float* Bb = Bm + (size_t)brow * L * DD;

    int tid = threadIdx.x;
    int tx = tid & 15, ty = tid >> 4;

    int ra[TI], lb[TJ];
#pragma unroll
    for (int i = 0; i < TI; ++i) ra[i] = min(ty + 16 * i, R - 1);  // clamp: always in-bounds
#pragma unroll
    for (int j = 0; j < TJ; ++j) lb[j] = min(tx + 16 * j, L - 1);

    float acc[TI][TJ];
#pragma unroll
    for (int i = 0; i < TI; ++i)
#pragma unroll
        for (int j = 0; j < TJ; ++j) acc[i][j] = 0.f;

    for (int c = 0; c < DD / CH; ++c) {
        int d0 = c * CH;
        for (int idx = tid; idx < R * CH; idx += 256) {
            int r = idx >> 6, dd = idx & 63;
            As[r][dd] = Ab[(size_t)r * DD + d0 + dd];
        }
        for (int idx = tid; idx < L * CH; idx += 256) {
            int r = idx >> 6, dd = idx & 63;
            Bs[r][dd] = Bb[(size_t)r * DD + d0 + dd];
        }
        __syncthreads();
#pragma unroll
        for (int dd = 0; dd < CH; dd += 4) {
            float4 av[TI], bv[TJ];
#pragma unroll
            for (int i = 0; i < TI; ++i) av[i] = *reinterpret_cast<const float4*>(&As[ra[i]][dd]);
#pragma unroll
            for (int j = 0; j < TJ; ++j) bv[j] = *reinterpret_cast<const float4*>(&Bs[lb[j]][dd]);
#pragma unroll
            for (int i = 0; i < TI; ++i)
#pragma unroll
                for (int j = 0; j < TJ; ++j) {
                    acc[i][j] = fmaf(av[i].x, bv[j].x, acc[i][j]);
                    acc[i][j] = fmaf(av[i].y, bv[j].y, acc[i][j]);
                    acc[i][j] = fmaf(av[i].z, bv[j].z, acc[i][j]);
                    acc[i][j] = fmaf(av[i].w, bv[j].w, acc[i][j]);
                }
        }
        __syncthreads();
    }

    // epilogue: cos matrix into reused As storage (R*(L+1) <= R*CHP), then max_r / sum_l
    float* cosS = &As[0][0];
    constexpr int LS = L + 1;
    float ia[TI];
#pragma unroll
    for (int i = 0; i < TI; ++i) ia[i] = invA[n * R + ra[i]];
#pragma unroll
    for (int j = 0; j < TJ; ++j) {
        float ib = invB[brow * L + lb[j]];
#pragma unroll
        for (int i = 0; i < TI; ++i) {
            int r = ty + 16 * i, l = tx + 16 * j;
            if (r < R && l < L) cosS[r * LS + l] = acc[i][j] * ia[i] * ib;
        }
    }
    __syncthreads();
    if (tid < L) {
        float m = -INFINITY;
        for (int r = 0; r < R; ++r) m = fmaxf(m, cosS[r * LS + tid]);
        colmax[tid] = m;
    }
    __syncthreads();
    if (tid == 0) {
        float s = 0.f;
        for (int l = 0; l < L; ++l) s += colmax[l];
        out[t] = s;
    }
}

// ---------------- top-3 per row (strict >, first occurrence on ties) ----------------
__global__ void topk_kernel(const float* __restrict__ sim, float* __restrict__ vals,
                            int* __restrict__ outidx) {
    int n = threadIdx.x; // 256 threads, one row each
    const float* row = sim + (size_t)n * NB;
    float v0 = -INFINITY, v1 = -INFINITY, v2 = -INFINITY;
    int i0 = 0, i1 = 0, i2 = 0;
    for (int p = 0; p < NB; ++p) {
        float v = row[p];
        if (v > v0)      { v2 = v1; i2 = i1; v1 = v0; i1 = i0; v0 = v; i0 = p; }
        else if (v > v1) { v2 = v1; i2 = i1; v1 = v;  i1 = p; }
        else if (v > v2) { v2 = v;  i2 = p; }
    }
    vals[n * 3 + 0] = v0; vals[n * 3 + 1] = v1; vals[n * 3 + 2] = v2;
    outidx[n * 3 + 0] = i0; outidx[n * 3 + 1] = i1; outidx[n * 3 + 2] = i2;
}

// ---------------- KL(p || q) with p=softmax(m1k/T), log q=log_softmax(m2k/T) ----------------
__global__ void loss_kernel(const float* __restrict__ m1k, const float* __restrict__ m2k,
                            float* __restrict__ out) {
    int n = threadIdx.x; // 256
    float a[3], b[3];
#pragma unroll
    for (int i = 0; i < 3; ++i) {
        a[i] = m1k[n * 3 + i] * (1.0f / TAU);
        b[i] = m2k[n * 3 + i] * (1.0f / TAU);
    }
    float am = fmaxf(a[0], fmaxf(a[1], a[2]));
    float bm = fmaxf(b[0], fmaxf(b[1], b[2]));
    float ase = expf(a[0] - am) + expf(a[1] - am) + expf(a[2] - am);
    float bse = expf(b[0] - bm) + expf(b[1] - bm) + expf(b[2] - bm);
    float alse = am + logf(ase);
    float blse = bm + logf(bse);
    float acc = 0.f;
#pragma unroll
    for (int i = 0; i < 3; ++i) {
        float lp = a[i] - alse, lq = b[i] - blse;
        acc += expf(lp) * (lp - lq);
    }
#pragma unroll
    for (int off = 32; off; off >>= 1) acc += __shfl_down(acc, off);
    __shared__ float w[4];
    if ((threadIdx.x & 63) == 0) w[threadIdx.x >> 6] = acc;
    __syncthreads();
    if (threadIdx.x == 0) atomicAdd(out, w[0] + w[1] + w[2] + w[3]);
}

extern "C" void kernel_launch(void* const* d_in, const int* in_sizes, int n_in,
                              void* d_out, int out_size, void* d_ws, size_t ws_size,
                              hipStream_t stream) {
    const float* img_n = (const float*)d_in[0];   // [256,36,1024]
    const float* cap_n = (const float*)d_in[1];   // [256,32,1024]
    const float* img_p = (const float*)d_in[2];   // [256,36,1024]
    const float* cap_p = (const float*)d_in[3];   // [256,32,1024]
    float* out = (float*)d_out;

    float* ws = (float*)d_ws;
    float* inv_im_n  = ws; ws += NB * 36;
    float* inv_cap_n = ws; ws += NB * 32;
    float* inv_im_p  = ws; ws += NB * 36;
    float* inv_cap_p = ws; ws += NB * 32;
    float* sim1 = ws; ws += NB * NB;
    float* sim2 = ws; ws += NB * NB;
    float* m1k1 = ws; ws += NB * 3;
    float* m2k1 = ws; ws += NB * 3;
    float* m1k2 = ws; ws += NB * 3;
    float* m2k2 = ws; ws += NB * 3;
    int* idx1 = (int*)ws; ws += NB * 3;
    int* idx2 = (int*)ws; ws += NB * 3;

    hipMemsetAsync(d_out, 0, sizeof(float), stream);

    invnorm_kernel<<<NB * 36, 64, 0, stream>>>(img_n, inv_im_n);
    invnorm_kernel<<<NB * 32, 64, 0, stream>>>(cap_n, inv_cap_n);
    invnorm_kernel<<<NB * 36, 64, 0, stream>>>(img_p, inv_im_p);
    invnorm_kernel<<<NB * 32, 64, 0, stream>>>(cap_p, inv_cap_p);

    // call 1: semantic_transfer_loss(img_n, img_p, cap_p)
    blocksim_kernel<36, 36><<<NB * NB, 256, 0, stream>>>(img_n, inv_im_n, img_p, inv_im_p,
                                                         nullptr, NB, sim1);
    topk_kernel<<<1, NB, 0, stream>>>(sim1, m1k1, idx1);
    blocksim_kernel<36, 32><<<NB * KSEL, 256, 0, stream>>>(img_n, inv_im_n, cap_p, inv_cap_p,
                                                           idx1, KSEL, m2k1);
    loss_kernel<<<1, NB, 0, stream>>>(m1k1, m2k1, out);

    // call 2: semantic_transfer_loss(cap_n, cap_p, img_p)
    blocksim_kernel<32, 32><<<NB * NB, 256, 0, stream>>>(cap_n, inv_cap_n, cap_p, inv_cap_p,
                                                         nullptr, NB, sim2);
    topk_kernel<<<1, NB, 0, stream>>>(sim2, m1k2, idx2);
    blocksim_kernel<32, 36><<<NB * KSEL, 256, 0, stream>>>(cap_n, inv_cap_n, img_p, inv_im_p,
                                                           idx2, KSEL, m2k2);
    loss_kernel<<<1, NB, 0, stream>>>(m1k2, m2k2, out);
}

// Round 2
// 1986.775 us; speedup vs baseline: 6.6685x; 6.6685x over previous
//
#include <hip/hip_runtime.h>
#include <math.h>

#define TAU 3.0f
#define NB 256          // batch
#define DD 1024         // embedding dim
#define KSEL 3

typedef _Float16 half8 __attribute__((ext_vector_type(8)));
typedef _Float16 half4 __attribute__((ext_vector_type(4)));
typedef float f32x4 __attribute__((ext_vector_type(4)));

// ---------------- fp32 normalize + f16 hi/lo split + inv-norm ----------------
// one block per row; 256 threads x 4 elems
__global__ __launch_bounds__(256) void norm_split_kernel(
    const float* __restrict__ x, _Float16* __restrict__ hi, _Float16* __restrict__ lo,
    float* __restrict__ inv)
{
    int row = blockIdx.x;
    int tid = threadIdx.x;
    const float* p = x + (size_t)row * DD;
    float4 v = reinterpret_cast<const float4*>(p)[tid];
    float ss = fmaf(v.x, v.x, fmaf(v.y, v.y, fmaf(v.z, v.z, v.w * v.w)));
#pragma unroll
    for (int off = 32; off; off >>= 1) ss += __shfl_down(ss, off);
    __shared__ float red[4];
    if ((tid & 63) == 0) red[tid >> 6] = ss;
    __syncthreads();
    float tot = red[0] + red[1] + red[2] + red[3];
    float nrm = fmaxf(sqrtf(tot), 1e-8f);
    if (tid == 0) inv[row] = 1.0f / nrm;
    float xn[4] = { v.x / nrm, v.y / nrm, v.z / nrm, v.w / nrm };
    half4 h, l;
#pragma unroll
    for (int i = 0; i < 4; ++i) {
        _Float16 hh = (_Float16)xn[i];
        h[i] = hh;
        l[i] = (_Float16)(xn[i] - (float)hh);
    }
    *reinterpret_cast<half4*>(hi + (size_t)row * DD + tid * 4) = h;
    *reinterpret_cast<half4*>(lo + (size_t)row * DD + tid * 4) = l;
}

// ---------------- stage-1 sims via f16-split MFMA ----------------
// Pairwise block-sim as padded GEMM with fused max_r / sum_l epilogue.
// RR = A rows/pair, LL = B rows/pair, PRM/PRN = pairs per tile in M/N.
// Normalized hi/lo f16 planes in; sim[NB][NB] out.
template<int RR, int LL, int PRM, int PRN>
__global__ __launch_bounds__(256, 2) void mfma_sim_kernel(
    const _Float16* __restrict__ Ah, const _Float16* __restrict__ Al,
    const _Float16* __restrict__ Bh, const _Float16* __restrict__ Bl,
    float* __restrict__ sim)
{
    constexpr int PMp = ((RR + 15) / 16) * 16;      // padded pair span (48 or 32)
    constexpr int PNp = ((LL + 15) / 16) * 16;
    constexpr int TM = PRM * PMp, TN = PRN * PNp;   // tile dims
    constexpr int WMS = TM / 2, WNS = TN / 2;       // wave spans (2x2 wave grid)
    constexpr int MF = WMS / 16, NF = WNS / 16;     // frags per wave
    constexpr int FPM = PMp / 16, FPN = PNp / 16;   // frags per pair
    constexpr int NPW = WMS / PMp, PPW = WNS / PNp; // pairs per wave

    __shared__ __align__(16) _Float16 AS[2][TM][64];
    __shared__ __align__(16) _Float16 BS[2][TN][64];

    const int bm = blockIdx.x, bn = blockIdx.y;
    const int tid = threadIdx.x;
    const int lane = tid & 63, wv = tid >> 6;
    const int wm = wv >> 1, wn = wv & 1;
    const int col = lane & 15, grp = lane >> 4;

    f32x4 acc[MF][NF];
#pragma unroll
    for (int i = 0; i < MF; ++i)
#pragma unroll
        for (int j = 0; j < NF; ++j) acc[i][j] = (f32x4)0.f;

    for (int c = 0; c < 16; ++c) {
        const int kb = c << 6;
        // stage A (real rows only; pad rows stay garbage, masked in epilogue)
        for (int idx = tid; idx < PRM * RR * 8; idx += 256) {
            int rowr = idx >> 3, c8 = idx & 7;
            int nl = rowr / RR, rr = rowr - nl * RR;
            size_t src = ((size_t)((bm * PRM + nl) * RR + rr) << 10) + kb + (c8 << 3);
            int drow = nl * PMp + rr;
            int inner = c8 ^ (drow & 7);
            *reinterpret_cast<uint4*>(&AS[0][drow][inner << 3]) =
                *reinterpret_cast<const uint4*>(Ah + src);
            *reinterpret_cast<uint4*>(&AS[1][drow][inner << 3]) =
                *reinterpret_cast<const uint4*>(Al + src);
        }
        for (int idx = tid; idx < PRN * LL * 8; idx += 256) {
            int rowr = idx >> 3, c8 = idx & 7;
            int nl = rowr / LL, rr = rowr - nl * LL;
            size_t src = ((size_t)((bn * PRN + nl) * LL + rr) << 10) + kb + (c8 << 3);
            int drow = nl * PNp + rr;
            int inner = c8 ^ (drow & 7);
            *reinterpret_cast<uint4*>(&BS[0][drow][inner << 3]) =
                *reinterpret_cast<const uint4*>(Bh + src);
            *reinterpret_cast<uint4*>(&BS[1][drow][inner << 3]) =
                *reinterpret_cast<const uint4*>(Bl + src);
        }
        __syncthreads();
#pragma unroll
        for (int ks = 0; ks < 2; ++ks) {
            half8 af[2][MF], bf[2][NF];
#pragma unroll
            for (int fm = 0; fm < MF; ++fm) {
                int row = wm * WMS + fm * 16 + col;
                int inner = (grp + ks * 4) ^ (row & 7);
                af[0][fm] = *reinterpret_cast<const half8*>(&AS[0][row][inner << 3]);
                af[1][fm] = *reinterpret_cast<const half8*>(&AS[1][row][inner << 3]);
            }
#pragma unroll
            for (int fn = 0; fn < NF; ++fn) {
                int row = wn * WNS + fn * 16 + col;
                int inner = (grp + ks * 4) ^ (row & 7);
                bf[0][fn] = *reinterpret_cast<const half8*>(&BS[0][row][inner << 3]);
                bf[1][fn] = *reinterpret_cast<const half8*>(&BS[1][row][inner << 3]);
            }
#pragma unroll
            for (int fm = 0; fm < MF; ++fm)
#pragma unroll
                for (int fn = 0; fn < NF; ++fn) {
                    acc[fm][fn] = __builtin_amdgcn_mfma_f32_16x16x32_f16(
                        af[0][fm], bf[0][fn], acc[fm][fn], 0, 0, 0);
                    acc[fm][fn] = __builtin_amdgcn_mfma_f32_16x16x32_f16(
                        af[0][fm], bf[1][fn], acc[fm][fn], 0, 0, 0);
                    acc[fm][fn] = __builtin_amdgcn_mfma_f32_16x16x32_f16(
                        af[1][fm], bf[0][fn], acc[fm][fn], 0, 0, 0);
                }
        }
        __syncthreads();
    }

    // epilogue: per column, max over real m rows; then masked sum over l; shuffle-only
#pragma unroll
    for (int np = 0; np < NPW; ++np) {
        float mxv[NF];
#pragma unroll
        for (int fn = 0; fn < NF; ++fn) {
            float m = -INFINITY;
#pragma unroll
            for (int fi = 0; fi < FPM; ++fi) {
#pragma unroll
                for (int r = 0; r < 4; ++r) {
                    int ml = fi * 16 + grp * 4 + r;
                    if ((RR % 16 == 0) || (ml < RR))
                        m = fmaxf(m, acc[np * FPM + fi][fn][r]);
                }
            }
            m = fmaxf(m, __shfl_xor(m, 16));
            m = fmaxf(m, __shfl_xor(m, 32));
            mxv[fn] = m;
        }
#pragma unroll
        for (int pp = 0; pp < PPW; ++pp) {
            float s = 0.f;
#pragma unroll
            for (int fj = 0; fj < FPN; ++fj) {
                int ll = fj * 16 + col;
                s += ((LL % 16 == 0) || (ll < LL)) ? mxv[pp * FPN + fj] : 0.f;
            }
            s += __shfl_xor(s, 1);
            s += __shfl_xor(s, 2);
            s += __shfl_xor(s, 4);
            s += __shfl_xor(s, 8);
            if (lane == 0) {
                int ng = bm * PRM + wm * NPW + np;
                int pg = bn * PRN + wn * PPW + pp;
                sim[(size_t)ng * NB + pg] = s;
            }
        }
    }
}

// ---------------- fp32 pairwise block-sim (stage-2 only: 768 blocks) ----------------
template<int R, int L>
__global__ __launch_bounds__(256) void blocksim_kernel(
    const float* __restrict__ A, const float* __restrict__ invA,
    const float* __restrict__ Bm, const float* __restrict__ invB,
    const int* __restrict__ bsel, int P, float* __restrict__ out)
{
    constexpr int CH = 64, CHP = 68;
    constexpr int TI = (R + 15) / 16, TJ = (L + 15) / 16;
    __shared__ __align__(16) float As[R][CHP];
    __shared__ __align__(16) float Bs[L][CHP];
    __shared__ float colmax[L];

    int t = blockIdx.x;
    int n = t / P;
    int pk = t - n * P;
    int brow = bsel ? bsel[t] : pk;

    const float* Ab = A + (size_t)n * R * DD;
    const float* Bb = Bm + (size_t)brow * L * DD;

    int tid = threadIdx.x;
    int tx = tid & 15, ty = tid >> 4;

    int ra[TI], lb[TJ];
#pragma unroll
    for (int i = 0; i < TI; ++i) ra[i] = min(ty + 16 * i, R - 1);
#pragma unroll
    for (int j = 0; j < TJ; ++j) lb[j] = min(tx + 16 * j, L - 1);

    float acc[TI][TJ];
#pragma unroll
    for (int i = 0; i < TI; ++i)
#pragma unroll
        for (int j = 0; j < TJ; ++j) acc[i][j] = 0.f;

    for (int c = 0; c < DD / CH; ++c) {
        int d0 = c * CH;
        for (int idx = tid; idx < R * CH; idx += 256) {
            int r = idx >> 6, dd = idx & 63;
            As[r][dd] = Ab[(size_t)r * DD + d0 + dd];
        }
        for (int idx = tid; idx < L * CH; idx += 256) {
            int r = idx >> 6, dd = idx & 63;
            Bs[r][dd] = Bb[(size_t)r * DD + d0 + dd];
        }
        __syncthreads();
#pragma unroll
        for (int dd = 0; dd < CH; dd += 4) {
            float4 av[TI], bv[TJ];
#pragma unroll
            for (int i = 0; i < TI; ++i) av[i] = *reinterpret_cast<const float4*>(&As[ra[i]][dd]);
#pragma unroll
            for (int j = 0; j < TJ; ++j) bv[j] = *reinterpret_cast<const float4*>(&Bs[lb[j]][dd]);
#pragma unroll
            for (int i = 0; i < TI; ++i)
#pragma unroll
                for (int j = 0; j < TJ; ++j) {
                    acc[i][j] = fmaf(av[i].x, bv[j].x, acc[i][j]);
                    acc[i][j] = fmaf(av[i].y, bv[j].y, acc[i][j]);
                    acc[i][j] = fmaf(av[i].z, bv[j].z, acc[i][j]);
                    acc[i][j] = fmaf(av[i].w, bv[j].w, acc[i][j]);
                }
        }
        __syncthreads();
    }

    float* cosS = &As[0][0];
    constexpr int LS = L + 1;
    float ia[TI];
#pragma unroll
    for (int i = 0; i < TI; ++i) ia[i] = invA[n * R + ra[i]];
#pragma unroll
    for (int j = 0; j < TJ; ++j) {
        float ib = invB[brow * L + lb[j]];
#pragma unroll
        for (int i = 0; i < TI; ++i) {
            int r = ty + 16 * i, l = tx + 16 * j;
            if (r < R && l < L) cosS[r * LS + l] = acc[i][j] * ia[i] * ib;
        }
    }
    __syncthreads();
    if (tid < L) {
        float m = -INFINITY;
        for (int r = 0; r < R; ++r) m = fmaxf(m, cosS[r * LS + tid]);
        colmax[tid] = m;
    }
    __syncthreads();
    if (tid == 0) {
        float s = 0.f;
        for (int l = 0; l < L; ++l) s += colmax[l];
        out[t] = s;
    }
}

// ---------------- top-3 per row (strict >, first occurrence on ties) ----------------
__global__ void topk_kernel(const float* __restrict__ sim, float* __restrict__ vals,
                            int* __restrict__ outidx) {
    int n = threadIdx.x;
    const float* row = sim + (size_t)n * NB;
    float v0 = -INFINITY, v1 = -INFINITY, v2 = -INFINITY;
    int i0 = 0, i1 = 0, i2 = 0;
    for (int p = 0; p < NB; ++p) {
        float v = row[p];
        if (v > v0)      { v2 = v1; i2 = i1; v1 = v0; i1 = i0; v0 = v; i0 = p; }
        else if (v > v1) { v2 = v1; i2 = i1; v1 = v;  i1 = p; }
        else if (v > v2) { v2 = v;  i2 = p; }
    }
    vals[n * 3 + 0] = v0; vals[n * 3 + 1] = v1; vals[n * 3 + 2] = v2;
    outidx[n * 3 + 0] = i0; outidx[n * 3 + 1] = i1; outidx[n * 3 + 2] = i2;
}

// ---------------- KL(p || q) ----------------
__global__ void loss_kernel(const float* __restrict__ m1k, const float* __restrict__ m2k,
                            float* __restrict__ out) {
    int n = threadIdx.x;
    float a[3], b[3];
#pragma unroll
    for (int i = 0; i < 3; ++i) {
        a[i] = m1k[n * 3 + i] * (1.0f / TAU);
        b[i] = m2k[n * 3 + i] * (1.0f / TAU);
    }
    float am = fmaxf(a[0], fmaxf(a[1], a[2]));
    float bm = fmaxf(b[0], fmaxf(b[1], b[2]));
    float ase = expf(a[0] - am) + expf(a[1] - am) + expf(a[2] - am);
    float bse = expf(b[0] - bm) + expf(b[1] - bm) + expf(b[2] - bm);
    float alse = am + logf(ase);
    float blse = bm + logf(bse);
    float acc = 0.f;
#pragma unroll
    for (int i = 0; i < 3; ++i) {
        float lp = a[i] - alse, lq = b[i] - blse;
        acc += expf(lp) * (lp - lq);
    }
#pragma unroll
    for (int off = 32; off; off >>= 1) acc += __shfl_down(acc, off);
    __shared__ float w[4];
    if ((threadIdx.x & 63) == 0) w[threadIdx.x >> 6] = acc;
    __syncthreads();
    if (threadIdx.x == 0) atomicAdd(out, w[0] + w[1] + w[2] + w[3]);
}

extern "C" void kernel_launch(void* const* d_in, const int* in_sizes, int n_in,
                              void* d_out, int out_size, void* d_ws, size_t ws_size,
                              hipStream_t stream) {
    const float* img_n = (const float*)d_in[0];   // [256,36,1024]
    const float* cap_n = (const float*)d_in[1];   // [256,32,1024]
    const float* img_p = (const float*)d_in[2];   // [256,36,1024]
    const float* cap_p = (const float*)d_in[3];   // [256,32,1024]
    float* out = (float*)d_out;

    char* w = (char*)d_ws;
    auto alloc = [&](size_t bytes) -> char* {
        char* p = w;
        w += (bytes + 255) & ~(size_t)255;
        return p;
    };
    const size_t IMGE = (size_t)NB * 36 * DD;   // img elems
    const size_t CAPE = (size_t)NB * 32 * DD;

    _Float16* imgN_h = (_Float16*)alloc(IMGE * 2);
    _Float16* imgN_l = (_Float16*)alloc(IMGE * 2);
    _Float16* imgP_h = (_Float16*)alloc(IMGE * 2);
    _Float16* imgP_l = (_Float16*)alloc(IMGE * 2);
    _Float16* capN_h = (_Float16*)alloc(CAPE * 2);
    _Float16* capN_l = (_Float16*)alloc(CAPE * 2);
    _Float16* capP_h = (_Float16*)alloc(CAPE * 2);
    _Float16* capP_l = (_Float16*)alloc(CAPE * 2);

    float* inv_im_n  = (float*)alloc(NB * 36 * 4);
    float* inv_cap_n = (float*)alloc(NB * 32 * 4);
    float* inv_im_p  = (float*)alloc(NB * 36 * 4);
    float* inv_cap_p = (float*)alloc(NB * 32 * 4);
    float* sim1 = (float*)alloc(NB * NB * 4);
    float* sim2 = (float*)alloc(NB * NB * 4);
    float* m1k1 = (float*)alloc(NB * 3 * 4);
    float* m2k1 = (float*)alloc(NB * 3 * 4);
    float* m1k2 = (float*)alloc(NB * 3 * 4);
    float* m2k2 = (float*)alloc(NB * 3 * 4);
    int* idx1 = (int*)alloc(NB * 3 * 4);
    int* idx2 = (int*)alloc(NB * 3 * 4);

    hipMemsetAsync(d_out, 0, sizeof(float), stream);

    norm_split_kernel<<<NB * 36, 256, 0, stream>>>(img_n, imgN_h, imgN_l, inv_im_n);
    norm_split_kernel<<<NB * 36, 256, 0, stream>>>(img_p, imgP_h, imgP_l, inv_im_p);
    norm_split_kernel<<<NB * 32, 256, 0, stream>>>(cap_n, capN_h, capN_l, inv_cap_n);
    norm_split_kernel<<<NB * 32, 256, 0, stream>>>(cap_p, capP_h, capP_l, inv_cap_p);

    // call 1: semantic_transfer_loss(img_n, img_p, cap_p) — 36x36 pairs
    mfma_sim_kernel<36, 36, 4, 2><<<dim3(NB / 4, NB / 2), 256, 0, stream>>>(
        imgN_h, imgN_l, imgP_h, imgP_l, sim1);
    topk_kernel<<<1, NB, 0, stream>>>(sim1, m1k1, idx1);
    blocksim_kernel<36, 32><<<NB * KSEL, 256, 0, stream>>>(img_n, inv_im_n, cap_p, inv_cap_p,
                                                           idx1, KSEL, m2k1);
    loss_kernel<<<1, NB, 0, stream>>>(m1k1, m2k1, out);

    // call 2: semantic_transfer_loss(cap_n, cap_p, img_p) — 32x32 pairs
    mfma_sim_kernel<32, 32, 4, 4><<<dim3(NB / 4, NB / 4), 256, 0, stream>>>(
        capN_h, capN_l, capP_h, capP_l, sim2);
    topk_kernel<<<1, NB, 0, stream>>>(sim2, m1k2, idx2);
    blocksim_kernel<32, 36><<<NB * KSEL, 256, 0, stream>>>(cap_n, inv_cap_n, img_p, inv_im_p,
                                                           idx2, KSEL, m2k2);
    loss_kernel<<<1, NB, 0, stream>>>(m1k2, m2k2, out);
}

// Round 3
// 1715.570 us; speedup vs baseline: 7.7226x; 1.1581x over previous
//
#include <hip/hip_runtime.h>
#include <math.h>

#define TAU 3.0f
#define NB 256          // batch
#define DD 1024         // embedding dim
#define KSEL 3

typedef _Float16 half8 __attribute__((ext_vector_type(8)));
typedef _Float16 half4 __attribute__((ext_vector_type(4)));
typedef float f32x4 __attribute__((ext_vector_type(4)));

__device__ __forceinline__ void gload_lds16(const void* g, void* l) {
    __builtin_amdgcn_global_load_lds(
        (const __attribute__((address_space(1))) unsigned int*)g,
        (__attribute__((address_space(3))) unsigned int*)l, 16, 0, 0);
}

// ---------------- fp32 normalize + f16 hi/lo split + inv-norm ----------------
__global__ __launch_bounds__(256) void norm_split_kernel(
    const float* __restrict__ x, _Float16* __restrict__ hi, _Float16* __restrict__ lo,
    float* __restrict__ inv)
{
    int row = blockIdx.x;
    int tid = threadIdx.x;
    const float* p = x + (size_t)row * DD;
    float4 v = reinterpret_cast<const float4*>(p)[tid];
    float ss = fmaf(v.x, v.x, fmaf(v.y, v.y, fmaf(v.z, v.z, v.w * v.w)));
#pragma unroll
    for (int off = 32; off; off >>= 1) ss += __shfl_down(ss, off);
    __shared__ float red[4];
    if ((tid & 63) == 0) red[tid >> 6] = ss;
    __syncthreads();
    float tot = red[0] + red[1] + red[2] + red[3];
    float nrm = fmaxf(sqrtf(tot), 1e-8f);
    if (tid == 0) inv[row] = 1.0f / nrm;
    float xn[4] = { v.x / nrm, v.y / nrm, v.z / nrm, v.w / nrm };
    half4 h, l;
#pragma unroll
    for (int i = 0; i < 4; ++i) {
        _Float16 hh = (_Float16)xn[i];
        h[i] = hh;
        l[i] = (_Float16)(xn[i] - (float)hh);
    }
    *reinterpret_cast<half4*>(hi + (size_t)row * DD + tid * 4) = h;
    *reinterpret_cast<half4*>(lo + (size_t)row * DD + tid * 4) = l;
}

// ---------------- stage-1 sim: unpadded f16-split MFMA GEMM, grouped epilogue ----------------
// C = Ah.Bh^T + Ah.Bl^T + Al.Bh^T over [TM x TN] tiles; epilogue: per G-row-group
// column max (row groups never straddle tiles: G | TM), then per G-col-group sum
// added to sim via atomicAdd (col groups may straddle tiles).
template<int G, int TM, int TN, int WGM, int WGN, int THREADS>
__global__ __launch_bounds__(THREADS) void mfma_sim_kernel(
    const _Float16* __restrict__ Ah, const _Float16* __restrict__ Al,
    const _Float16* __restrict__ Bh, const _Float16* __restrict__ Bl,
    float* __restrict__ sim)
{
    constexpr int WAVES = WGM * WGN;
    static_assert(THREADS == WAVES * 64, "bad thread count");
    constexpr int WMS = TM / WGM, WNS = TN / WGN;
    constexpr int MF = WMS / 16, NF = WNS / 16;
    constexpr int ABYTES = 2 * TM * 128;           // 2 planes x TM rows x 64 f16 x 2B
    constexpr int BBYTES = 2 * TN * 128;
    constexpr int NREG = (ABYTES + BBYTES) / 1024; // 1KB wave-load regions per K-chunk
    constexpr int AREG = ABYTES / 1024;
    constexpr int GM = TM / G;
    static_assert(TM % G == 0, "row groups must align");
    static_assert((ABYTES + BBYTES) % 1024 == 0, "");

    __shared__ __align__(16) char LDSBUF[ABYTES + BBYTES];

    const int bm = blockIdx.y, bn = blockIdx.x;
    const int tid = threadIdx.x;
    const int lane = tid & 63, wv = tid >> 6;
    const int wm = wv / WGN, wn = wv % WGN;
    const int col = lane & 15, grp = lane >> 4;

    f32x4 acc[MF][NF];
#pragma unroll
    for (int i = 0; i < MF; ++i)
#pragma unroll
        for (int j = 0; j < NF; ++j) acc[i][j] = (f32x4)0.f;

    const int srow = lane >> 3;   // row within 8-row 1KB region
    const int sj = lane & 7;      // 16B chunk within row

    for (int c = 0; c < 16; ++c) {
        const int kb = c << 6;
        // stage via global_load_lds: linear LDS dest, source 16B-chunk XOR-preswizzled
        for (int reg = wv; reg < NREG; reg += WAVES) {
            bool isB = reg >= AREG;
            int r2 = isB ? reg - AREG : reg;
            int rpp = isB ? (TN >> 3) : (TM >> 3);
            int plane = r2 / rpp;
            int rowt = ((r2 - plane * rpp) << 3) + srow;
            int c8 = sj ^ (rowt & 7);
            const _Float16* base = isB ? (plane ? Bl : Bh) : (plane ? Al : Ah);
            int rowg = (isB ? bn * TN : bm * TM) + rowt;
            const _Float16* src = base + (((size_t)rowg) << 10) + kb + (c8 << 3);
            gload_lds16(src, LDSBUF + reg * 1024);
        }
        __syncthreads();   // compiler emits vmcnt(0) drain before barrier

        const char* LA = LDSBUF;
        const char* LB = LDSBUF + ABYTES;
#pragma unroll
        for (int ks = 0; ks < 2; ++ks) {
            half8 af[2][MF], bf[2][NF];
#pragma unroll
            for (int fm = 0; fm < MF; ++fm) {
                int row = wm * WMS + fm * 16 + col;
                int j = (grp + ks * 4) ^ (row & 7);
                af[0][fm] = *(const half8*)(LA + row * 128 + j * 16);
                af[1][fm] = *(const half8*)(LA + TM * 128 + row * 128 + j * 16);
            }
#pragma unroll
            for (int fn = 0; fn < NF; ++fn) {
                int row = wn * WNS + fn * 16 + col;
                int j = (grp + ks * 4) ^ (row & 7);
                bf[0][fn] = *(const half8*)(LB + row * 128 + j * 16);
                bf[1][fn] = *(const half8*)(LB + TN * 128 + row * 128 + j * 16);
            }
#pragma unroll
            for (int fm = 0; fm < MF; ++fm)
#pragma unroll
                for (int fn = 0; fn < NF; ++fn) {
                    acc[fm][fn] = __builtin_amdgcn_mfma_f32_16x16x32_f16(
                        af[0][fm], bf[0][fn], acc[fm][fn], 0, 0, 0);
                    acc[fm][fn] = __builtin_amdgcn_mfma_f32_16x16x32_f16(
                        af[0][fm], bf[1][fn], acc[fm][fn], 0, 0, 0);
                    acc[fm][fn] = __builtin_amdgcn_mfma_f32_16x16x32_f16(
                        af[1][fm], bf[0][fn], acc[fm][fn], 0, 0, 0);
                }
        }
        __syncthreads();
    }

    // ---- epilogue: per-4row-chunk max (4 | G so chunks never straddle groups) ----
    float* cm = (float*)LDSBUF;                 // [TM/4][TN]
    float* colmax = cm + (TM / 4) * TN;         // [GM][TN]
#pragma unroll
    for (int fm = 0; fm < MF; ++fm) {
        int rc = (wm * WMS + fm * 16) / 4 + grp;
#pragma unroll
        for (int fn = 0; fn < NF; ++fn) {
            f32x4 v = acc[fm][fn];
            float m = fmaxf(fmaxf(v[0], v[1]), fmaxf(v[2], v[3]));
            int ct = wn * WNS + fn * 16 + col;
            cm[rc * TN + ct] = m;
        }
    }
    __syncthreads();
    for (int idx = tid; idx < GM * TN; idx += THREADS) {
        int gm = idx / TN, cc = idx - gm * TN;
        float m = -INFINITY;
#pragma unroll
        for (int k = 0; k < G / 4; ++k) m = fmaxf(m, cm[(gm * (G / 4) + k) * TN + cc]);
        colmax[gm * TN + cc] = m;
    }
    __syncthreads();
    // per (row-group, col-group-segment) partial sums -> atomicAdd into sim
    int pc0 = bn * TN;
    int p0 = pc0 / G;
    for (int item = tid; item < GM * 8; item += THREADS) {
        int gm = item >> 3, s = item & 7;
        int p = p0 + s;
        int cs = p * G - pc0, ce = cs + G;
        cs = cs < 0 ? 0 : cs;
        ce = ce > TN ? TN : ce;
        if (cs < ce && p < NB) {
            float sum = 0.f;
            for (int cc = cs; cc < ce; ++cc) sum += colmax[gm * TN + cc];
            atomicAdd(&sim[(size_t)(bm * GM + gm) * NB + p], sum);
        }
    }
}

// ---------------- fp32 pairwise block-sim (stage-2 only: 768 blocks) ----------------
template<int R, int L>
__global__ __launch_bounds__(256) void blocksim_kernel(
    const float* __restrict__ A, const float* __restrict__ invA,
    const float* __restrict__ Bm, const float* __restrict__ invB,
    const int* __restrict__ bsel, int P, float* __restrict__ out)
{
    constexpr int CH = 64, CHP = 68;
    constexpr int TI = (R + 15) / 16, TJ = (L + 15) / 16;
    __shared__ __align__(16) float As[R][CHP];
    __shared__ __align__(16) float Bs[L][CHP];
    __shared__ float colmax[L];

    int t = blockIdx.x;
    int n = t / P;
    int pk = t - n * P;
    int brow = bsel ? bsel[t] : pk;

    const float* Ab = A + (size_t)n * R * DD;
    const float* Bb = Bm + (size_t)brow * L * DD;

    int tid = threadIdx.x;
    int tx = tid & 15, ty = tid >> 4;

    int ra[TI], lb[TJ];
#pragma unroll
    for (int i = 0; i < TI; ++i) ra[i] = min(ty + 16 * i, R - 1);
#pragma unroll
    for (int j = 0; j < TJ; ++j) lb[j] = min(tx + 16 * j, L - 1);

    float acc[TI][TJ];
#pragma unroll
    for (int i = 0; i < TI; ++i)
#pragma unroll
        for (int j = 0; j < TJ; ++j) acc[i][j] = 0.f;

    for (int c = 0; c < DD / CH; ++c) {
        int d0 = c * CH;
        for (int idx = tid; idx < R * CH; idx += 256) {
            int r = idx >> 6, dd = idx & 63;
            As[r][dd] = Ab[(size_t)r * DD + d0 + dd];
        }
        for (int idx = tid; idx < L * CH; idx += 256) {
            int r = idx >> 6, dd = idx & 63;
            Bs[r][dd] = Bb[(size_t)r * DD + d0 + dd];
        }
        __syncthreads();
#pragma unroll
        for (int dd = 0; dd < CH; dd += 4) {
            float4 av[TI], bv[TJ];
#pragma unroll
            for (int i = 0; i < TI; ++i) av[i] = *reinterpret_cast<const float4*>(&As[ra[i]][dd]);
#pragma unroll
            for (int j = 0; j < TJ; ++j) bv[j] = *reinterpret_cast<const float4*>(&Bs[lb[j]][dd]);
#pragma unroll
            for (int i = 0; i < TI; ++i)
#pragma unroll
                for (int j = 0; j < TJ; ++j) {
                    acc[i][j] = fmaf(av[i].x, bv[j].x, acc[i][j]);
                    acc[i][j] = fmaf(av[i].y, bv[j].y, acc[i][j]);
                    acc[i][j] = fmaf(av[i].z, bv[j].z, acc[i][j]);
                    acc[i][j] = fmaf(av[i].w, bv[j].w, acc[i][j]);
                }
        }
        __syncthreads();
    }

    float* cosS = &As[0][0];
    constexpr int LS = L + 1;
    float ia[TI];
#pragma unroll
    for (int i = 0; i < TI; ++i) ia[i] = invA[n * R + ra[i]];
#pragma unroll
    for (int j = 0; j < TJ; ++j) {
        float ib = invB[brow * L + lb[j]];
#pragma unroll
        for (int i = 0; i < TI; ++i) {
            int r = ty + 16 * i, l = tx + 16 * j;
            if (r < R && l < L) cosS[r * LS + l] = acc[i][j] * ia[i] * ib;
        }
    }
    __syncthreads();
    if (tid < L) {
        float m = -INFINITY;
        for (int r = 0; r < R; ++r) m = fmaxf(m, cosS[r * LS + tid]);
        colmax[tid] = m;
    }
    __syncthreads();
    if (tid == 0) {
        float s = 0.f;
        for (int l = 0; l < L; ++l) s += colmax[l];
        out[t] = s;
    }
}

// ---------------- top-3 per row (strict >, first occurrence on ties) ----------------
__global__ void topk_kernel(const float* __restrict__ sim, float* __restrict__ vals,
                            int* __restrict__ outidx) {
    int n = threadIdx.x;
    const float* row = sim + (size_t)n * NB;
    float v0 = -INFINITY, v1 = -INFINITY, v2 = -INFINITY;
    int i0 = 0, i1 = 0, i2 = 0;
    for (int p = 0; p < NB; ++p) {
        float v = row[p];
        if (v > v0)      { v2 = v1; i2 = i1; v1 = v0; i1 = i0; v0 = v; i0 = p; }
        else if (v > v1) { v2 = v1; i2 = i1; v1 = v;  i1 = p; }
        else if (v > v2) { v2 = v;  i2 = p; }
    }
    vals[n * 3 + 0] = v0; vals[n * 3 + 1] = v1; vals[n * 3 + 2] = v2;
    outidx[n * 3 + 0] = i0; outidx[n * 3 + 1] = i1; outidx[n * 3 + 2] = i2;
}

// ---------------- KL(p || q) ----------------
__global__ void loss_kernel(const float* __restrict__ m1k, const float* __restrict__ m2k,
                            float* __restrict__ out) {
    int n = threadIdx.x;
    float a[3], b[3];
#pragma unroll
    for (int i = 0; i < 3; ++i) {
        a[i] = m1k[n * 3 + i] * (1.0f / TAU);
        b[i] = m2k[n * 3 + i] * (1.0f / TAU);
    }
    float am = fmaxf(a[0], fmaxf(a[1], a[2]));
    float bm = fmaxf(b[0], fmaxf(b[1], b[2]));
    float ase = expf(a[0] - am) + expf(a[1] - am) + expf(a[2] - am);
    float bse = expf(b[0] - bm) + expf(b[1] - bm) + expf(b[2] - bm);
    float alse = am + logf(ase);
    float blse = bm + logf(bse);
    float acc = 0.f;
#pragma unroll
    for (int i = 0; i < 3; ++i) {
        float lp = a[i] - alse, lq = b[i] - blse;
        acc += expf(lp) * (lp - lq);
    }
#pragma unroll
    for (int off = 32; off; off >>= 1) acc += __shfl_down(acc, off);
    __shared__ float w[4];
    if ((threadIdx.x & 63) == 0) w[threadIdx.x >> 6] = acc;
    __syncthreads();
    if (threadIdx.x == 0) atomicAdd(out, w[0] + w[1] + w[2] + w[3]);
}

extern "C" void kernel_launch(void* const* d_in, const int* in_sizes, int n_in,
                              void* d_out, int out_size, void* d_ws, size_t ws_size,
                              hipStream_t stream) {
    const float* img_n = (const float*)d_in[0];   // [256,36,1024]
    const float* cap_n = (const float*)d_in[1];   // [256,32,1024]
    const float* img_p = (const float*)d_in[2];   // [256,36,1024]
    const float* cap_p = (const float*)d_in[3];   // [256,32,1024]
    float* out = (float*)d_out;

    char* w = (char*)d_ws;
    auto alloc = [&](size_t bytes) -> char* {
        char* p = w;
        w += (bytes + 255) & ~(size_t)255;
        return p;
    };
    const size_t IMGE = (size_t)NB * 36 * DD;
    const size_t CAPE = (size_t)NB * 32 * DD;

    _Float16* imgN_h = (_Float16*)alloc(IMGE * 2);
    _Float16* imgN_l = (_Float16*)alloc(IMGE * 2);
    _Float16* imgP_h = (_Float16*)alloc(IMGE * 2);
    _Float16* imgP_l = (_Float16*)alloc(IMGE * 2);
    _Float16* capN_h = (_Float16*)alloc(CAPE * 2);
    _Float16* capN_l = (_Float16*)alloc(CAPE * 2);
    _Float16* capP_h = (_Float16*)alloc(CAPE * 2);
    _Float16* capP_l = (_Float16*)alloc(CAPE * 2);

    float* inv_im_n  = (float*)alloc(NB * 36 * 4);
    float* inv_cap_n = (float*)alloc(NB * 32 * 4);
    float* inv_im_p  = (float*)alloc(NB * 36 * 4);
    float* inv_cap_p = (float*)alloc(NB * 32 * 4);
    float* sim1 = (float*)alloc(NB * NB * 4);
    float* sim2 = (float*)alloc(NB * NB * 4);
    float* m1k1 = (float*)alloc(NB * 3 * 4);
    float* m2k1 = (float*)alloc(NB * 3 * 4);
    float* m1k2 = (float*)alloc(NB * 3 * 4);
    float* m2k2 = (float*)alloc(NB * 3 * 4);
    int* idx1 = (int*)alloc(NB * 3 * 4);
    int* idx2 = (int*)alloc(NB * 3 * 4);

    hipMemsetAsync(d_out, 0, sizeof(float), stream);
    hipMemsetAsync(sim1, 0, (size_t)NB * NB * 4, stream);
    hipMemsetAsync(sim2, 0, (size_t)NB * NB * 4, stream);

    norm_split_kernel<<<NB * 36, 256, 0, stream>>>(img_n, imgN_h, imgN_l, inv_im_n);
    norm_split_kernel<<<NB * 36, 256, 0, stream>>>(img_p, imgP_h, imgP_l, inv_im_p);
    norm_split_kernel<<<NB * 32, 256, 0, stream>>>(cap_n, capN_h, capN_l, inv_cap_n);
    norm_split_kernel<<<NB * 32, 256, 0, stream>>>(cap_p, capP_h, capP_l, inv_cap_p);

    // call 1: semantic_transfer_loss(img_n, img_p, cap_p) — 9216x9216, G=36
    mfma_sim_kernel<36, 144, 128, 3, 2, 384><<<dim3(72, 64), 384, 0, stream>>>(
        imgN_h, imgN_l, imgP_h, imgP_l, sim1);
    topk_kernel<<<1, NB, 0, stream>>>(sim1, m1k1, idx1);
    blocksim_kernel<36, 32><<<NB * KSEL, 256, 0, stream>>>(img_n, inv_im_n, cap_p, inv_cap_p,
                                                           idx1, KSEL, m2k1);
    loss_kernel<<<1, NB, 0, stream>>>(m1k1, m2k1, out);

    // call 2: semantic_transfer_loss(cap_n, cap_p, img_p) — 8192x8192, G=32
    mfma_sim_kernel<32, 128, 128, 2, 2, 256><<<dim3(64, 64), 256, 0, stream>>>(
        capN_h, capN_l, capP_h, capP_l, sim2);
    topk_kernel<<<1, NB, 0, stream>>>(sim2, m1k2, idx2);
    blocksim_kernel<32, 36><<<NB * KSEL, 256, 0, stream>>>(cap_n, inv_cap_n, img_p, inv_im_p,
                                                           idx2, KSEL, m2k2);
    loss_kernel<<<1, NB, 0, stream>>>(m1k2, m2k2, out);
}

// Round 5
// 1227.829 us; speedup vs baseline: 10.7904x; 1.3972x over previous
//
#include <hip/hip_runtime.h>
#include <math.h>

#define TAU 3.0f
#define NB 256          // batch
#define DD 1024         // embedding dim
#define KSEL 3

typedef _Float16 half8 __attribute__((ext_vector_type(8)));
typedef _Float16 half4 __attribute__((ext_vector_type(4)));
typedef float f32x4 __attribute__((ext_vector_type(4)));

__device__ __forceinline__ void gload_lds16(const void* g, void* l) {
    __builtin_amdgcn_global_load_lds(
        (const __attribute__((address_space(1))) unsigned int*)g,
        (__attribute__((address_space(3))) unsigned int*)l, 16, 0, 0);
}

// order-preserving float <-> u32 (for atomicMax on floats of any sign)
__device__ __forceinline__ unsigned int fenc(float x) {
    unsigned int u = __float_as_uint(x);
    return u ^ (((unsigned int)((int)u >> 31)) | 0x80000000u);
}
__device__ __forceinline__ float fdec(unsigned int e) {
    unsigned int u = (e & 0x80000000u) ? (e ^ 0x80000000u) : ~e;
    return __uint_as_float(u);
}

// ---------------- fp32 normalize + f16 hi/lo split + inv-norm ----------------
__global__ __launch_bounds__(256) void norm_split_kernel(
    const float* __restrict__ x, _Float16* __restrict__ hi, _Float16* __restrict__ lo,
    float* __restrict__ inv)
{
    int row = blockIdx.x;
    int tid = threadIdx.x;
    const float* p = x + (size_t)row * DD;
    float4 v = reinterpret_cast<const float4*>(p)[tid];
    float ss = fmaf(v.x, v.x, fmaf(v.y, v.y, fmaf(v.z, v.z, v.w * v.w)));
#pragma unroll
    for (int off = 32; off; off >>= 1) ss += __shfl_down(ss, off);
    __shared__ float red[4];
    if ((tid & 63) == 0) red[tid >> 6] = ss;
    __syncthreads();
    float tot = red[0] + red[1] + red[2] + red[3];
    float nrm = fmaxf(sqrtf(tot), 1e-8f);
    if (tid == 0) inv[row] = 1.0f / nrm;
    float xn[4] = { v.x / nrm, v.y / nrm, v.z / nrm, v.w / nrm };
    half4 h, l;
#pragma unroll
    for (int i = 0; i < 4; ++i) {
        _Float16 hh = (_Float16)xn[i];
        h[i] = hh;
        l[i] = (_Float16)(xn[i] - (float)hh);
    }
    *reinterpret_cast<half4*>(hi + (size_t)row * DD + tid * 4) = h;
    *reinterpret_cast<half4*>(lo + (size_t)row * DD + tid * 4) = l;
}

// ---------------- stage-1 GEMM: 192x192 tile, dbuf prefetch, f16-split MFMA ----------------
// Output: per (row-group g, col c) partial max -> global atomicMax(cmax[g*Wc + col], enc).
// LDS swizzle: 64B rows, 16B chunks; chunk position = gchunk ^ ((row>>1)&3) so that 16
// consecutive rows x 4 chunk-positions cover all 8 16B-slots of each 128B bank span 2x (free).
template<int G, int THREADS>
__global__ __launch_bounds__(THREADS, 1) void mfma_simX_kernel(
    const _Float16* __restrict__ Ah, const _Float16* __restrict__ Al,
    const _Float16* __restrict__ Bh, const _Float16* __restrict__ Bl,
    unsigned int* __restrict__ cmax, int Wc)
{
    constexpr int TM = 192, TN = 192, WGM = 2, WGN = 3, WAVES = 6;
    static_assert(THREADS == WAVES * 64, "");
    constexpr int WMS = TM / WGM;        // 96
    constexpr int WNS = TN / WGN;        // 64
    constexpr int MF = WMS / 16;         // 6
    constexpr int NF = WNS / 16;         // 4
    constexpr int KCH = 32, NCH = DD / KCH;
    constexpr int ABYT = 2 * TM * 64;    // 2 planes x 192 rows x 64B
    constexpr int BBYT = 2 * TN * 64;
    constexpr int BUFB = ABYT + BBYT;    // 49152
    constexpr int NREG = BUFB / 1024;    // 48
    constexpr int RPW = NREG / WAVES;    // 8

    __shared__ __align__(16) char LDSB[2 * BUFB];   // 96 KiB dbuf

    const int bm = blockIdx.y, bn = blockIdx.x;
    const int tid = threadIdx.x;
    const int lane = tid & 63, wv = tid >> 6;
    const int wm = wv / WGN, wn = wv % WGN;
    const int col = lane & 15, grp = lane >> 4;

    // per-wave staging descriptors (hoisted). Lane l covers region row rr=l>>2,
    // LDS chunk-pos l&3; fetch global chunk (l&3) ^ ((rr>>1)&3) = (l&3) ^ ((l>>3)&3).
    const _Float16* srcp[RPW];
    int ldsoff[RPW];
    const int swz = ((lane & 3) ^ ((lane >> 3) & 3)) << 3;   // f16 elems (x2B = 16B chunks)
#pragma unroll
    for (int i = 0; i < RPW; ++i) {
        int r = wv + i * WAVES;          // 0..47
        int arr = r / 12;                // 0:Ah 1:Al 2:Bh 3:Bl (12 regions per plane)
        int rip = (r % 12) * 16 + (lane >> 2);
        int grow = (arr < 2 ? bm * TM : bn * TN) + rip;
        const _Float16* base = (arr == 0) ? Ah : (arr == 1) ? Al : (arr == 2) ? Bh : Bl;
        srcp[i] = base + (((size_t)grow) << 10) + swz;
        ldsoff[i] = r * 1024;
    }

    f32x4 acc[MF][NF];
#pragma unroll
    for (int i = 0; i < MF; ++i)
#pragma unroll
        for (int j = 0; j < NF; ++j) acc[i][j] = (f32x4)0.f;

    // prologue: stage chunk 0 into buf0
#pragma unroll
    for (int i = 0; i < RPW; ++i) gload_lds16(srcp[i], LDSB + ldsoff[i]);
    __syncthreads();

    for (int c = 0; c < NCH; ++c) {
        const int cb = c & 1;
        if (c + 1 < NCH) {
            const int nbuf = cb ^ 1;
#pragma unroll
            for (int i = 0; i < RPW; ++i)
                gload_lds16(srcp[i] + (c + 1) * KCH, LDSB + nbuf * BUFB + ldsoff[i]);
        }
        const char* LA  = LDSB + cb * BUFB;
        const char* LAl = LA + TM * 64;
        const char* LB  = LA + ABYT;
        const char* LBl = LB + TN * 64;

        half8 bh[NF], bl_[NF];
#pragma unroll
        for (int fn = 0; fn < NF; ++fn) {
            int row = wn * WNS + fn * 16 + col;
            int j = (grp ^ ((row >> 1) & 3)) << 4;
            bh[fn]  = *(const half8*)(LB  + row * 64 + j);
            bl_[fn] = *(const half8*)(LBl + row * 64 + j);
        }
#pragma unroll
        for (int fm = 0; fm < MF; ++fm) {
            int row = wm * WMS + fm * 16 + col;
            int j = (grp ^ ((row >> 1) & 3)) << 4;
            half8 ah  = *(const half8*)(LA  + row * 64 + j);
            half8 al_ = *(const half8*)(LAl + row * 64 + j);
#pragma unroll
            for (int fn = 0; fn < NF; ++fn) {
                acc[fm][fn] = __builtin_amdgcn_mfma_f32_16x16x32_f16(ah,  bh[fn],  acc[fm][fn], 0, 0, 0);
                acc[fm][fn] = __builtin_amdgcn_mfma_f32_16x16x32_f16(ah,  bl_[fn], acc[fm][fn], 0, 0, 0);
                acc[fm][fn] = __builtin_amdgcn_mfma_f32_16x16x32_f16(al_, bh[fn],  acc[fm][fn], 0, 0, 0);
            }
        }
        __syncthreads();
    }

    // epilogue: per-4row-chunk col max into LDS (stride padded +1), then group-slice
    // maxes -> global atomicMax (order-preserving encoding).
    float* cm = (float*)LDSB;            // [TM/4][TN+1]
    constexpr int CMS = TN + 1;
#pragma unroll
    for (int fm = 0; fm < MF; ++fm) {
        int rc = ((wm * WMS + fm * 16) >> 2) + grp;
#pragma unroll
        for (int fn = 0; fn < NF; ++fn) {
            f32x4 v = acc[fm][fn];
            float m = fmaxf(fmaxf(v[0], v[1]), fmaxf(v[2], v[3]));
            cm[rc * CMS + wn * WNS + fn * 16 + col] = m;
        }
    }
    __syncthreads();
    const int mrow0 = bm * TM;
    const int g0 = mrow0 / G;
    const int g1 = (mrow0 + TM - 1) / G;
    const int ngs = g1 - g0 + 1;
    for (int it = tid; it < ngs * TN; it += THREADS) {
        int gi = it / TN, cc = it - gi * TN;
        int g = g0 + gi;
        int rs = g * G;        if (rs < mrow0) rs = mrow0;
        int re = (g + 1) * G;  if (re > mrow0 + TM) re = mrow0 + TM;
        float m = -INFINITY;
        int rc0 = (rs - mrow0) >> 2, rc1 = (re - mrow0) >> 2;
        for (int rc = rc0; rc < rc1; ++rc) m = fmaxf(m, cm[rc * CMS + cc]);
        atomicMax(&cmax[(size_t)g * Wc + bn * TN + cc], fenc(m));
    }
}

// ---------------- finish: decode cmax, sum over tokens -> sim ----------------
template<int G2>
__global__ void finish_kernel(const unsigned int* __restrict__ cmax, int Wc,
                              float* __restrict__ sim) {
    int n = blockIdx.x, p = threadIdx.x;   // 256 threads
    const unsigned int* row = cmax + (size_t)n * Wc + p * G2;
    float s = 0.f;
#pragma unroll
    for (int l = 0; l < G2; ++l) s += fdec(row[l]);
    sim[(size_t)n * NB + p] = s;
}

// ---------------- fp32 pairwise block-sim (stage-2 only: 768 blocks) ----------------
template<int R, int L>
__global__ __launch_bounds__(256) void blocksim_kernel(
    const float* __restrict__ A, const float* __restrict__ invA,
    const float* __restrict__ Bm, const float* __restrict__ invB,
    const int* __restrict__ bsel, int P, float* __restrict__ out)
{
    constexpr int CH = 64, CHP = 68;
    constexpr int TI = (R + 15) / 16, TJ = (L + 15) / 16;
    __shared__ __align__(16) float As[R][CHP];
    __shared__ __align__(16) float Bs[L][CHP];
    __shared__ float colmax[L];

    int t = blockIdx.x;
    int n = t / P;
    int pk = t - n * P;
    int brow = bsel ? bsel[t] : pk;

    const float* Ab = A + (size_t)n * R * DD;
    const float* Bb = Bm + (size_t)brow * L * DD;

    int tid = threadIdx.x;
    int tx = tid & 15, ty = tid >> 4;

    int ra[TI], lb[TJ];
#pragma unroll
    for (int i = 0; i < TI; ++i) ra[i] = min(ty + 16 * i, R - 1);
#pragma unroll
    for (int j = 0; j < TJ; ++j) lb[j] = min(tx + 16 * j, L - 1);

    float acc[TI][TJ];
#pragma unroll
    for (int i = 0; i < TI; ++i)
#pragma unroll
        for (int j = 0; j < TJ; ++j) acc[i][j] = 0.f;

    for (int c = 0; c < DD / CH; ++c) {
        int d0 = c * CH;
        for (int idx = tid; idx < R * CH; idx += 256) {
            int r = idx >> 6, dd = idx & 63;
            As[r][dd] = Ab[(size_t)r * DD + d0 + dd];
        }
        for (int idx = tid; idx < L * CH; idx += 256) {
            int r = idx >> 6, dd = idx & 63;
            Bs[r][dd] = Bb[(size_t)r * DD + d0 + dd];
        }
        __syncthreads();
#pragma unroll
        for (int dd = 0; dd < CH; dd += 4) {
            float4 av[TI], bv[TJ];
#pragma unroll
            for (int i = 0; i < TI; ++i) av[i] = *reinterpret_cast<const float4*>(&As[ra[i]][dd]);
#pragma unroll
            for (int j = 0; j < TJ; ++j) bv[j] = *reinterpret_cast<const float4*>(&Bs[lb[j]][dd]);
#pragma unroll
            for (int i = 0; i < TI; ++i)
#pragma unroll
                for (int j = 0; j < TJ; ++j) {
                    acc[i][j] = fmaf(av[i].x, bv[j].x, acc[i][j]);
                    acc[i][j] = fmaf(av[i].y, bv[j].y, acc[i][j]);
                    acc[i][j] = fmaf(av[i].z, bv[j].z, acc[i][j]);
                    acc[i][j] = fmaf(av[i].w, bv[j].w, acc[i][j]);
                }
        }
        __syncthreads();
    }

    float* cosS = &As[0][0];
    constexpr int LS = L + 1;
    float ia[TI];
#pragma unroll
    for (int i = 0; i < TI; ++i) ia[i] = invA[n * R + ra[i]];
#pragma unroll
    for (int j = 0; j < TJ; ++j) {
        float ib = invB[brow * L + lb[j]];
#pragma unroll
        for (int i = 0; i < TI; ++i) {
            int r = ty + 16 * i, l = tx + 16 * j;
            if (r < R && l < L) cosS[r * LS + l] = acc[i][j] * ia[i] * ib;
        }
    }
    __syncthreads();
    if (tid < L) {
        float m = -INFINITY;
        for (int r = 0; r < R; ++r) m = fmaxf(m, cosS[r * LS + tid]);
        colmax[tid] = m;
    }
    __syncthreads();
    if (tid == 0) {
        float s = 0.f;
        for (int l = 0; l < L; ++l) s += colmax[l];
        out[t] = s;
    }
}

// ---------------- wave-parallel top-3 per row (strict >, lowest index on ties) ----------------
__global__ void topk_kernel(const float* __restrict__ sim, float* __restrict__ vals,
                            int* __restrict__ outidx) {
    int n = blockIdx.x;
    int lane = threadIdx.x;   // 64
    float v0 = -INFINITY, v1 = -INFINITY, v2 = -INFINITY;
    int i0 = 0x7fffffff, i1 = 0x7fffffff, i2 = 0x7fffffff;
    for (int p = lane; p < NB; p += 64) {
        float v = sim[(size_t)n * NB + p];
        if (v > v0)      { v2 = v1; i2 = i1; v1 = v0; i1 = i0; v0 = v; i0 = p; }
        else if (v > v1) { v2 = v1; i2 = i1; v1 = v;  i1 = p; }
        else if (v > v2) { v2 = v;  i2 = p; }
    }
#pragma unroll
    for (int off = 32; off; off >>= 1) {
        float w0 = __shfl_down(v0, off), w1 = __shfl_down(v1, off), w2 = __shfl_down(v2, off);
        int   j0 = __shfl_down(i0, off), j1 = __shfl_down(i1, off), j2 = __shfl_down(i2, off);
#define INS3(w, j)                                                                   \
        if (w > v0 || (w == v0 && j < i0)) { v2=v1;i2=i1; v1=v0;i1=i0; v0=w;i0=j; }  \
        else if (w > v1 || (w == v1 && j < i1)) { v2=v1;i2=i1; v1=w;i1=j; }          \
        else if (w > v2 || (w == v2 && j < i2)) { v2=w;i2=j; }
        INS3(w0, j0); INS3(w1, j1); INS3(w2, j2);
#undef INS3
    }
    if (lane == 0) {
        vals[n * 3 + 0] = v0; vals[n * 3 + 1] = v1; vals[n * 3 + 2] = v2;
        outidx[n * 3 + 0] = i0; outidx[n * 3 + 1] = i1; outidx[n * 3 + 2] = i2;
    }
}

// ---------------- KL(p || q) ----------------
__global__ void loss_kernel(const float* __restrict__ m1k, const float* __restrict__ m2k,
                            float* __restrict__ out) {
    int n = threadIdx.x;
    float a[3], b[3];
#pragma unroll
    for (int i = 0; i < 3; ++i) {
        a[i] = m1k[n * 3 + i] * (1.0f / TAU);
        b[i] = m2k[n * 3 + i] * (1.0f / TAU);
    }
    float am = fmaxf(a[0], fmaxf(a[1], a[2]));
    float bm = fmaxf(b[0], fmaxf(b[1], b[2]));
    float ase = expf(a[0] - am) + expf(a[1] - am) + expf(a[2] - am);
    float bse = expf(b[0] - bm) + expf(b[1] - bm) + expf(b[2] - bm);
    float alse = am + logf(ase);
    float blse = bm + logf(bse);
    float acc = 0.f;
#pragma unroll
    for (int i = 0; i < 3; ++i) {
        float lp = a[i] - alse, lq = b[i] - blse;
        acc += expf(lp) * (lp - lq);
    }
#pragma unroll
    for (int off = 32; off; off >>= 1) acc += __shfl_down(acc, off);
    __shared__ float w[4];
    if ((threadIdx.x & 63) == 0) w[threadIdx.x >> 6] = acc;
    __syncthreads();
    if (threadIdx.x == 0) atomicAdd(out, w[0] + w[1] + w[2] + w[3]);
}

extern "C" void kernel_launch(void* const* d_in, const int* in_sizes, int n_in,
                              void* d_out, int out_size, void* d_ws, size_t ws_size,
                              hipStream_t stream) {
    const float* img_n = (const float*)d_in[0];   // [256,36,1024]
    const float* cap_n = (const float*)d_in[1];   // [256,32,1024]
    const float* img_p = (const float*)d_in[2];   // [256,36,1024]
    const float* cap_p = (const float*)d_in[3];   // [256,32,1024]
    float* out = (float*)d_out;

    char* w = (char*)d_ws;
    auto alloc = [&](size_t bytes) -> char* {
        char* p = w;
        w += (bytes + 255) & ~(size_t)255;
        return p;
    };
    const size_t IMGE  = (size_t)NB * 36 * DD;    // 9437184 (9216 rows, 48 tiles exactly)
    const size_t CAPE  = (size_t)NB * 32 * DD;    // 8388608 (8192 rows)
    const size_t CAPEP = (size_t)8256 * DD;       // padded to 43 tiles of 192

    _Float16* imgN_h = (_Float16*)alloc(IMGE * 2);
    _Float16* imgN_l = (_Float16*)alloc(IMGE * 2);
    _Float16* imgP_h = (_Float16*)alloc(IMGE * 2);
    _Float16* imgP_l = (_Float16*)alloc(IMGE * 2);
    _Float16* capN_h = (_Float16*)alloc(CAPEP * 2);
    _Float16* capN_l = (_Float16*)alloc(CAPEP * 2);
    _Float16* capP_h = (_Float16*)alloc(CAPEP * 2);
    _Float16* capP_l = (_Float16*)alloc(CAPEP * 2);

    // cmax1 and cmax2 have disjoint lifetimes -> share one region (max of the two sizes)
    const size_t CM1 = (size_t)256 * 9216 * 4;
    const size_t CM2 = (size_t)258 * 8256 * 4;
    unsigned int* cmaxbuf = (unsigned int*)alloc(CM1 > CM2 ? CM1 : CM2);

    float* inv_im_n  = (float*)alloc(NB * 36 * 4);
    float* inv_cap_n = (float*)alloc(NB * 32 * 4);
    float* inv_im_p  = (float*)alloc(NB * 36 * 4);
    float* inv_cap_p = (float*)alloc(NB * 32 * 4);
    float* sim1 = (float*)alloc(NB * NB * 4);
    float* sim2 = (float*)alloc(NB * NB * 4);
    float* m1k1 = (float*)alloc(NB * 3 * 4);
    float* m2k1 = (float*)alloc(NB * 3 * 4);
    float* m1k2 = (float*)alloc(NB * 3 * 4);
    float* m2k2 = (float*)alloc(NB * 3 * 4);
    int* idx1 = (int*)alloc(NB * 3 * 4);
    int* idx2 = (int*)alloc(NB * 3 * 4);

    hipMemsetAsync(d_out, 0, sizeof(float), stream);
    hipMemsetAsync(cmaxbuf, 0, CM1, stream);
    // zero the padded tail rows of cap splits (64 rows x 1024 f16 each)
    hipMemsetAsync(capN_h + CAPE, 0, (CAPEP - CAPE) * 2, stream);
    hipMemsetAsync(capN_l + CAPE, 0, (CAPEP - CAPE) * 2, stream);
    hipMemsetAsync(capP_h + CAPE, 0, (CAPEP - CAPE) * 2, stream);
    hipMemsetAsync(capP_l + CAPE, 0, (CAPEP - CAPE) * 2, stream);

    norm_split_kernel<<<NB * 36, 256, 0, stream>>>(img_n, imgN_h, imgN_l, inv_im_n);
    norm_split_kernel<<<NB * 36, 256, 0, stream>>>(img_p, imgP_h, imgP_l, inv_im_p);
    norm_split_kernel<<<NB * 32, 256, 0, stream>>>(cap_n, capN_h, capN_l, inv_cap_n);
    norm_split_kernel<<<NB * 32, 256, 0, stream>>>(cap_p, capP_h, capP_l, inv_cap_p);

    // call 1: semantic_transfer_loss(img_n, img_p, cap_p) — 9216x9216, G=36
    mfma_simX_kernel<36, 384><<<dim3(48, 48), 384, 0, stream>>>(
        imgN_h, imgN_l, imgP_h, imgP_l, cmaxbuf, 9216);
    finish_kernel<36><<<NB, NB, 0, stream>>>(cmaxbuf, 9216, sim1);
    hipMemsetAsync(cmaxbuf, 0, CM2, stream);   // re-zero for call 2 (after finish read)
    topk_kernel<<<NB, 64, 0, stream>>>(sim1, m1k1, idx1);
    blocksim_kernel<36, 32><<<NB * KSEL, 256, 0, stream>>>(img_n, inv_im_n, cap_p, inv_cap_p,
                                                           idx1, KSEL, m2k1);
    loss_kernel<<<1, NB, 0, stream>>>(m1k1, m2k1, out);

    // call 2: semantic_transfer_loss(cap_n, cap_p, img_p) — 8192x8192 (padded 8256), G=32
    mfma_simX_kernel<32, 384><<<dim3(43, 43), 384, 0, stream>>>(
        capN_h, capN_l, capP_h, capP_l, cmaxbuf, 8256);
    finish_kernel<32><<<NB, NB, 0, stream>>>(cmaxbuf, 8256, sim2);
    topk_kernel<<<NB, 64, 0, stream>>>(sim2, m1k2, idx2);
    blocksim_kernel<32, 36><<<NB * KSEL, 256, 0, stream>>>(cap_n, inv_cap_n, img_p, inv_im_p,
                                                           idx2, KSEL, m2k2);
    loss_kernel<<<1, NB, 0, stream>>>(m1k2, m2k2, out);
}

// Round 8
// 1042.954 us; speedup vs baseline: 12.7031x; 1.1773x over previous
//
#include <hip/hip_runtime.h>
#include <math.h>

#define TAU 3.0f
#define NB 256          // batch
#define DD 1024         // embedding dim
#define KSEL 3

typedef _Float16 half8 __attribute__((ext_vector_type(8)));
typedef _Float16 half4 __attribute__((ext_vector_type(4)));
typedef float f32x4 __attribute__((ext_vector_type(4)));

__device__ __forceinline__ void gload_lds16(const void* g, void* l) {
    __builtin_amdgcn_global_load_lds(
        (const __attribute__((address_space(1))) unsigned int*)g,
        (__attribute__((address_space(3))) unsigned int*)l, 16, 0, 0);
}

// order-preserving float <-> u32 (for atomicMax on floats of any sign)
__device__ __forceinline__ unsigned int fenc(float x) {
    unsigned int u = __float_as_uint(x);
    return u ^ (((unsigned int)((int)u >> 31)) | 0x80000000u);
}
__device__ __forceinline__ float fdec(unsigned int e) {
    unsigned int u = (e & 0x80000000u) ? (e ^ 0x80000000u) : ~e;
    return __uint_as_float(u);
}

// ---------------- fp32 normalize + f16 hi/lo split ----------------
__global__ __launch_bounds__(256) void norm_split_kernel(
    const float* __restrict__ x, _Float16* __restrict__ hi, _Float16* __restrict__ lo)
{
    int row = blockIdx.x;
    int tid = threadIdx.x;
    const float* p = x + (size_t)row * DD;
    float4 v = reinterpret_cast<const float4*>(p)[tid];
    float ss = fmaf(v.x, v.x, fmaf(v.y, v.y, fmaf(v.z, v.z, v.w * v.w)));
#pragma unroll
    for (int off = 32; off; off >>= 1) ss += __shfl_down(ss, off);
    __shared__ float red[4];
    if ((tid & 63) == 0) red[tid >> 6] = ss;
    __syncthreads();
    float tot = red[0] + red[1] + red[2] + red[3];
    float nrm = fmaxf(sqrtf(tot), 1e-8f);
    float xn[4] = { v.x / nrm, v.y / nrm, v.z / nrm, v.w / nrm };
    half4 h, l;
#pragma unroll
    for (int i = 0; i < 4; ++i) {
        _Float16 hh = (_Float16)xn[i];
        h[i] = hh;
        l[i] = (_Float16)(xn[i] - (float)hh);
    }
    *reinterpret_cast<half4*>(hi + (size_t)row * DD + tid * 4) = h;
    *reinterpret_cast<half4*>(lo + (size_t)row * DD + tid * 4) = l;
}

// ---------------- stage-1 GEMM: 128x160 tile, 2 blocks/CU, dbuf prefetch ----------------
// f16-split (3 products); per (row-group g, col) partial max -> atomicMax(cmax).
template<int G>
__global__ __launch_bounds__(256, 2) void mfma_simX_kernel(
    const _Float16* __restrict__ Ah, const _Float16* __restrict__ Al,
    const _Float16* __restrict__ Bh, const _Float16* __restrict__ Bl,
    unsigned int* __restrict__ cmax, int Wc)
{
    constexpr int TM = 128, TN = 160, WAVES = 4, THREADS = 256;
    constexpr int WMS = 64, WNS = 80;    // 2x2 wave grid
    constexpr int MF = 4, NF = 5;
    constexpr int KCH = 32, NCH = DD / KCH;
    constexpr int ABYT = 2 * TM * 64;    // 16384
    constexpr int BBYT = 2 * TN * 64;    // 20480
    constexpr int BUFB = ABYT + BBYT;    // 36864
    constexpr int NREG = BUFB / 1024;    // 36
    constexpr int RPW = NREG / WAVES;    // 9

    __shared__ __align__(16) char LDSB[2 * BUFB];   // 72 KiB dbuf

    const int bm = blockIdx.y, bn = blockIdx.x;
    const int tid = threadIdx.x;
    const int lane = tid & 63, wv = tid >> 6;
    const int wm = wv >> 1, wn = wv & 1;
    const int col = lane & 15, grp = lane >> 4;

    // staging descriptors (hoisted). Region = 16 rows x 64B. Lane l -> row l>>2,
    // LDS chunk-pos l&3; fetch global chunk (l&3) ^ ((row>>1)&3) = (l&3)^((l>>3)&3).
    const _Float16* srcp[RPW];
    int ldsoff[RPW];
    const int swz = ((lane & 3) ^ ((lane >> 3) & 3)) << 3;   // f16 elems
#pragma unroll
    for (int i = 0; i < RPW; ++i) {
        int r = wv + i * WAVES;          // 0..35
        bool isB = r >= 16;
        int rr = isB ? r - 16 : r;
        int rpp = isB ? 10 : 8;
        int plane = rr / rpp;
        int rip = (rr - plane * rpp) * 16 + (lane >> 2);
        const _Float16* base = isB ? (plane ? Bl : Bh) : (plane ? Al : Ah);
        int grow = (isB ? bn * TN : bm * TM) + rip;
        srcp[i] = base + (((size_t)grow) << 10) + swz;
        ldsoff[i] = r * 1024;
    }

    f32x4 acc[MF][NF];
#pragma unroll
    for (int i = 0; i < MF; ++i)
#pragma unroll
        for (int j = 0; j < NF; ++j) acc[i][j] = (f32x4)0.f;

    // prologue: stage chunk 0 into buf0
#pragma unroll
    for (int i = 0; i < RPW; ++i) gload_lds16(srcp[i], LDSB + ldsoff[i]);
    __syncthreads();

    for (int c = 0; c < NCH; ++c) {
        const int cb = c & 1;
        if (c + 1 < NCH) {
            const int nbuf = cb ^ 1;
#pragma unroll
            for (int i = 0; i < RPW; ++i)
                gload_lds16(srcp[i] + (c + 1) * KCH, LDSB + nbuf * BUFB + ldsoff[i]);
        }
        const char* LA  = LDSB + cb * BUFB;
        const char* LAl = LA + TM * 64;
        const char* LB  = LA + ABYT;
        const char* LBl = LB + TN * 64;

        half8 bh[NF], bl_[NF];
#pragma unroll
        for (int fn = 0; fn < NF; ++fn) {
            int row = wn * WNS + fn * 16 + col;
            int j = (grp ^ ((row >> 1) & 3)) << 4;
            bh[fn]  = *(const half8*)(LB  + row * 64 + j);
            bl_[fn] = *(const half8*)(LBl + row * 64 + j);
        }
        __builtin_amdgcn_s_setprio(1);
#pragma unroll
        for (int fm = 0; fm < MF; ++fm) {
            int row = wm * WMS + fm * 16 + col;
            int j = (grp ^ ((row >> 1) & 3)) << 4;
            half8 ah  = *(const half8*)(LA  + row * 64 + j);
            half8 al_ = *(const half8*)(LAl + row * 64 + j);
#pragma unroll
            for (int fn = 0; fn < NF; ++fn) {
                acc[fm][fn] = __builtin_amdgcn_mfma_f32_16x16x32_f16(ah,  bh[fn],  acc[fm][fn], 0, 0, 0);
                acc[fm][fn] = __builtin_amdgcn_mfma_f32_16x16x32_f16(ah,  bl_[fn], acc[fm][fn], 0, 0, 0);
                acc[fm][fn] = __builtin_amdgcn_mfma_f32_16x16x32_f16(al_, bh[fn],  acc[fm][fn], 0, 0, 0);
            }
        }
        __builtin_amdgcn_s_setprio(0);
        __syncthreads();
    }

    // epilogue: per-4row-chunk col max into LDS (padded stride), then group-slice
    // maxes -> global atomicMax (order-preserving encoding).
    float* cm = (float*)LDSB;            // [TM/4][TN+1]
    constexpr int CMS = TN + 1;
#pragma unroll
    for (int fm = 0; fm < MF; ++fm) {
        int rc = ((wm * WMS + fm * 16) >> 2) + grp;
#pragma unroll
        for (int fn = 0; fn < NF; ++fn) {
            f32x4 v = acc[fm][fn];
            float m = fmaxf(fmaxf(v[0], v[1]), fmaxf(v[2], v[3]));
            cm[rc * CMS + wn * WNS + fn * 16 + col] = m;
        }
    }
    __syncthreads();
    const int mrow0 = bm * TM;
    const int g0 = mrow0 / G;
    const int g1 = (mrow0 + TM - 1) / G;
    const int ngs = g1 - g0 + 1;
    for (int it = tid; it < ngs * TN; it += THREADS) {
        int gi = it / TN, cc = it - gi * TN;
        int g = g0 + gi;
        int rs = g * G;        if (rs < mrow0) rs = mrow0;
        int re = (g + 1) * G;  if (re > mrow0 + TM) re = mrow0 + TM;
        float m = -INFINITY;
        int rc0 = (rs - mrow0) >> 2, rc1 = (re - mrow0) >> 2;
        for (int rc = rc0; rc < rc1; ++rc) m = fmaxf(m, cm[rc * CMS + cc]);
        atomicMax(&cmax[(size_t)g * Wc + bn * TN + cc], fenc(m));
    }
}

// ---------------- fused finish + top-3 (strict >, lowest index on ties) ----------------
template<int G2>
__global__ __launch_bounds__(256) void finish_topk_kernel(
    const unsigned int* __restrict__ cmax, int Wc,
    float* __restrict__ vals, int* __restrict__ outidx)
{
    __shared__ float sims[NB];
    int n = blockIdx.x, p = threadIdx.x;
    const unsigned int* row = cmax + (size_t)n * Wc + (size_t)p * G2;
    float s = 0.f;
#pragma unroll
    for (int l = 0; l < G2; ++l) s += fdec(row[l]);
    sims[p] = s;
    __syncthreads();
    if (p < 64) {
        int lane = p;
        float v0 = -INFINITY, v1 = -INFINITY, v2 = -INFINITY;
        int i0 = 0x7fffffff, i1 = 0x7fffffff, i2 = 0x7fffffff;
        for (int q = lane; q < NB; q += 64) {
            float v = sims[q];
            if (v > v0)      { v2 = v1; i2 = i1; v1 = v0; i1 = i0; v0 = v; i0 = q; }
            else if (v > v1) { v2 = v1; i2 = i1; v1 = v;  i1 = q; }
            else if (v > v2) { v2 = v;  i2 = q; }
        }
#pragma unroll
        for (int off = 32; off; off >>= 1) {
            float w0 = __shfl_down(v0, off), w1 = __shfl_down(v1, off), w2 = __shfl_down(v2, off);
            int   j0 = __shfl_down(i0, off), j1 = __shfl_down(i1, off), j2 = __shfl_down(i2, off);
#define INS3(w, j)                                                                   \
            if (w > v0 || (w == v0 && j < i0)) { v2=v1;i2=i1; v1=v0;i1=i0; v0=w;i0=j; }  \
            else if (w > v1 || (w == v1 && j < i1)) { v2=v1;i2=i1; v1=w;i1=j; }          \
            else if (w > v2 || (w == v2 && j < i2)) { v2=w;i2=j; }
            INS3(w0, j0); INS3(w1, j1); INS3(w2, j2);
#undef INS3
        }
        if (lane == 0) {
            vals[n * 3 + 0] = v0; vals[n * 3 + 1] = v1; vals[n * 3 + 2] = v2;
            outidx[n * 3 + 0] = i0; outidx[n * 3 + 1] = i1; outidx[n * 3 + 2] = i2;
        }
    }
}

// ---------------- stage-2: hi-plane MFMA block-sim, 1 wave per (n,k) ----------------
// out[t] = sum_{l<L} max_r ( Ah[n,r,:] . Bh[bsel[t],l,:] )  (f16 hi only; err ~1e-4)
template<int R, int L>
__global__ __launch_bounds__(64) void stage2_kernel(
    const _Float16* __restrict__ Ah, const _Float16* __restrict__ Bh,
    const int* __restrict__ bsel, float* __restrict__ m2k)
{
    constexpr int MF = (R + 15) / 16, NF = (L + 15) / 16;
    int t = blockIdx.x;              // NB*KSEL
    int n = t / KSEL;
    int b = bsel[t];
    const _Float16* Ab = Ah + (size_t)n * R * DD;
    const _Float16* Bb = Bh + (size_t)b * L * DD;
    int lane = threadIdx.x;
    int col = lane & 15, grp = lane >> 4;

    int ra[MF], lb[NF];
#pragma unroll
    for (int i = 0; i < MF; ++i) ra[i] = min(i * 16 + col, R - 1);  // dup rows: max-safe
#pragma unroll
    for (int j = 0; j < NF; ++j) lb[j] = min(j * 16 + col, L - 1);  // dup cols: masked in sum

    f32x4 acc[MF][NF];
#pragma unroll
    for (int i = 0; i < MF; ++i)
#pragma unroll
        for (int j = 0; j < NF; ++j) acc[i][j] = (f32x4)0.f;

    for (int c = 0; c < DD / 32; ++c) {
        int k0 = c * 32 + grp * 8;
        half8 af[MF], bf[NF];
#pragma unroll
        for (int i = 0; i < MF; ++i) af[i] = *(const half8*)(Ab + (size_t)ra[i] * DD + k0);
#pragma unroll
        for (int j = 0; j < NF; ++j) bf[j] = *(const half8*)(Bb + (size_t)lb[j] * DD + k0);
#pragma unroll
        for (int i = 0; i < MF; ++i)
#pragma unroll
            for (int j = 0; j < NF; ++j)
                acc[i][j] = __builtin_amdgcn_mfma_f32_16x16x32_f16(af[i], bf[j], acc[i][j], 0, 0, 0);
    }

    float s = 0.f;
#pragma unroll
    for (int j = 0; j < NF; ++j) {
        float m = -INFINITY;
#pragma unroll
        for (int i = 0; i < MF; ++i) {
#pragma unroll
            for (int r = 0; r < 4; ++r) m = fmaxf(m, acc[i][j][r]);
        }
        m = fmaxf(m, __shfl_xor(m, 16));
        m = fmaxf(m, __shfl_xor(m, 32));
        if (j * 16 + col < L) s += m;
    }
    s += __shfl_xor(s, 1);
    s += __shfl_xor(s, 2);
    s += __shfl_xor(s, 4);
    s += __shfl_xor(s, 8);
    if (lane == 0) m2k[t] = s;
}

// ---------------- KL(p || q) ----------------
__global__ void loss_kernel(const float* __restrict__ m1k, const float* __restrict__ m2k,
                            float* __restrict__ out) {
    int n = threadIdx.x;
    float a[3], b[3];
#pragma unroll
    for (int i = 0; i < 3; ++i) {
        a[i] = m1k[n * 3 + i] * (1.0f / TAU);
        b[i] = m2k[n * 3 + i] * (1.0f / TAU);
    }
    float am = fmaxf(a[0], fmaxf(a[1], a[2]));
    float bm = fmaxf(b[0], fmaxf(b[1], b[2]));
    float ase = expf(a[0] - am) + expf(a[1] - am) + expf(a[2] - am);
    float bse = expf(b[0] - bm) + expf(b[1] - bm) + expf(b[2] - bm);
    float alse = am + logf(ase);
    float blse = bm + logf(bse);
    float acc = 0.f;
#pragma unroll
    for (int i = 0; i < 3; ++i) {
        float lp = a[i] - alse, lq = b[i] - blse;
        acc += expf(lp) * (lp - lq);
    }
#pragma unroll
    for (int off = 32; off; off >>= 1) acc += __shfl_down(acc, off);
    __shared__ float w[4];
    if ((threadIdx.x & 63) == 0) w[threadIdx.x >> 6] = acc;
    __syncthreads();
    if (threadIdx.x == 0) atomicAdd(out, w[0] + w[1] + w[2] + w[3]);
}

extern "C" void kernel_launch(void* const* d_in, const int* in_sizes, int n_in,
                              void* d_out, int out_size, void* d_ws, size_t ws_size,
                              hipStream_t stream) {
    const float* img_n = (const float*)d_in[0];   // [256,36,1024]
    const float* cap_n = (const float*)d_in[1];   // [256,32,1024]
    const float* img_p = (const float*)d_in[2];   // [256,36,1024]
    const float* cap_p = (const float*)d_in[3];   // [256,32,1024]
    float* out = (float*)d_out;

    char* w = (char*)d_ws;
    auto alloc = [&](size_t bytes) -> char* {
        char* p = w;
        w += (bytes + 255) & ~(size_t)255;
        return p;
    };
    const size_t IMGE   = (size_t)NB * 36 * DD;   // 9216 rows (72 x 128 M-tiles exact)
    const size_t CAPE   = (size_t)NB * 32 * DD;   // 8192 rows (64 x 128 exact)
    const size_t IMGPE  = (size_t)9280 * DD;      // img_p padded to 58 x 160 N-tiles
    const size_t CAPPE  = (size_t)8320 * DD;      // cap_p padded to 52 x 160 N-tiles
    const int WC1 = 9280, WC2 = 8320;

    _Float16* imgN_h = (_Float16*)alloc(IMGE * 2);
    _Float16* imgN_l = (_Float16*)alloc(IMGE * 2);
    _Float16* imgP_h = (_Float16*)alloc(IMGPE * 2);
    _Float16* imgP_l = (_Float16*)alloc(IMGPE * 2);
    _Float16* capN_h = (_Float16*)alloc(CAPE * 2);
    _Float16* capN_l = (_Float16*)alloc(CAPE * 2);
    _Float16* capP_h = (_Float16*)alloc(CAPPE * 2);
    _Float16* capP_l = (_Float16*)alloc(CAPPE * 2);

    const size_t CM1 = (size_t)256 * WC1 * 4;
    const size_t CM2 = (size_t)256 * WC2 * 4;
    unsigned int* cmax1 = (unsigned int*)alloc(CM1);
    unsigned int* cmax2 = (unsigned int*)alloc(CM2);

    float* m1k1 = (float*)alloc(NB * 3 * 4);
    float* m2k1 = (float*)alloc(NB * 3 * 4);
    float* m1k2 = (float*)alloc(NB * 3 * 4);
    float* m2k2 = (float*)alloc(NB * 3 * 4);
    int* idx1 = (int*)alloc(NB * 3 * 4);
    int* idx2 = (int*)alloc(NB * 3 * 4);

    hipMemsetAsync(d_out, 0, sizeof(float), stream);
    hipMemsetAsync(cmax1, 0, CM1, stream);
    hipMemsetAsync(cmax2, 0, CM2, stream);
    // zero padded B-row tails (fake columns, never read by finish)
    hipMemsetAsync(imgP_h + IMGE, 0, (IMGPE - IMGE) * 2, stream);
    hipMemsetAsync(imgP_l + IMGE, 0, (IMGPE - IMGE) * 2, stream);
    hipMemsetAsync(capP_h + CAPE, 0, (CAPPE - CAPE) * 2, stream);
    hipMemsetAsync(capP_l + CAPE, 0, (CAPPE - CAPE) * 2, stream);

    norm_split_kernel<<<NB * 36, 256, 0, stream>>>(img_n, imgN_h, imgN_l);
    norm_split_kernel<<<NB * 36, 256, 0, stream>>>(img_p, imgP_h, imgP_l);
    norm_split_kernel<<<NB * 32, 256, 0, stream>>>(cap_n, capN_h, capN_l);
    norm_split_kernel<<<NB * 32, 256, 0, stream>>>(cap_p, capP_h, capP_l);

    // call 1: semantic_transfer_loss(img_n, img_p, cap_p) — 9216x9280, G=36
    mfma_simX_kernel<36><<<dim3(58, 72), 256, 0, stream>>>(
        imgN_h, imgN_l, imgP_h, imgP_l, cmax1, WC1);
    finish_topk_kernel<36><<<NB, 256, 0, stream>>>(cmax1, WC1, m1k1, idx1);
    stage2_kernel<36, 32><<<NB * KSEL, 64, 0, stream>>>(imgN_h, capP_h, idx1, m2k1);
    loss_kernel<<<1, NB, 0, stream>>>(m1k1, m2k1, out);

    // call 2: semantic_transfer_loss(cap_n, cap_p, img_p) — 8192x8320, G=32
    mfma_simX_kernel<32><<<dim3(52, 64), 256, 0, stream>>>(
        capN_h, capN_l, capP_h, capP_l, cmax2, WC2);
    finish_topk_kernel<32><<<NB, 256, 0, stream>>>(cmax2, WC2, m1k2, idx2);
    stage2_kernel<32, 36><<<NB * KSEL, 64, 0, stream>>>(capN_h, imgP_h, idx2, m2k2);
    loss_kernel<<<1, NB, 0, stream>>>(m1k2, m2k2, out);
}

// Round 10
// 995.455 us; speedup vs baseline: 13.3092x; 1.0477x over previous
//
#include <hip/hip_runtime.h>
#include <math.h>

#define TAU 3.0f
#define NB 256          // batch
#define DD 1024         // embedding dim
#define KSEL 3

typedef _Float16 half8 __attribute__((ext_vector_type(8)));
typedef _Float16 half4 __attribute__((ext_vector_type(4)));
typedef float f32x4 __attribute__((ext_vector_type(4)));

__device__ __forceinline__ void gload_lds16(const void* g, void* l) {
    __builtin_amdgcn_global_load_lds(
        (const __attribute__((address_space(1))) unsigned int*)g,
        (__attribute__((address_space(3))) unsigned int*)l, 16, 0, 0);
}

// order-preserving float <-> u32 (for atomicMax on floats of any sign)
__device__ __forceinline__ unsigned int fenc(float x) {
    unsigned int u = __float_as_uint(x);
    return u ^ (((unsigned int)((int)u >> 31)) | 0x80000000u);
}
__device__ __forceinline__ float fdec(unsigned int e) {
    unsigned int u = (e & 0x80000000u) ? (e ^ 0x80000000u) : ~e;
    return __uint_as_float(u);
}

// ---------------- fp32 normalize + f16 hi/lo split ----------------
__global__ __launch_bounds__(256) void norm_split_kernel(
    const float* __restrict__ x, _Float16* __restrict__ hi, _Float16* __restrict__ lo)
{
    int row = blockIdx.x;
    int tid = threadIdx.x;
    const float* p = x + (size_t)row * DD;
    float4 v = reinterpret_cast<const float4*>(p)[tid];
    float ss = fmaf(v.x, v.x, fmaf(v.y, v.y, fmaf(v.z, v.z, v.w * v.w)));
#pragma unroll
    for (int off = 32; off; off >>= 1) ss += __shfl_down(ss, off);
    __shared__ float red[4];
    if ((tid & 63) == 0) red[tid >> 6] = ss;
    __syncthreads();
    float tot = red[0] + red[1] + red[2] + red[3];
    float nrm = fmaxf(sqrtf(tot), 1e-8f);
    float xn[4] = { v.x / nrm, v.y / nrm, v.z / nrm, v.w / nrm };
    half4 h, l;
#pragma unroll
    for (int i = 0; i < 4; ++i) {
        _Float16 hh = (_Float16)xn[i];
        h[i] = hh;
        l[i] = (_Float16)(xn[i] - (float)hh);
    }
    *reinterpret_cast<half4*>(hi + (size_t)row * DD + tid * 4) = h;
    *reinterpret_cast<half4*>(lo + (size_t)row * DD + tid * 4) = l;
}

// ---------------- stage-1 GEMM: 128x160 tile, 2 blocks/CU, dbuf prefetch ----------------
// Block mapping: XCD-contiguous chunks (T1) + GROUP_M=8 raster (bm fastest) so the 8
// readers of each B panel are consecutive on one XCD (L2 hits) and the band's 8 A
// panels (4MB) stay L2-resident. f16-split (3 products); per (row-group g, col)
// partial max -> atomicMax(cmax).
template<int G, int NBM, int NBN>
__global__ __launch_bounds__(256, 2) void mfma_simX_kernel(
    const _Float16* __restrict__ Ah, const _Float16* __restrict__ Al,
    const _Float16* __restrict__ Bh, const _Float16* __restrict__ Bl,
    unsigned int* __restrict__ cmax, int Wc)
{
    constexpr int TM = 128, TN = 160, WAVES = 4, THREADS = 256;
    constexpr int WMS = 64, WNS = 80;    // 2x2 wave grid
    constexpr int MF = 4, NF = 5;
    constexpr int KCH = 32, NCH = DD / KCH;
    constexpr int ABYT = 2 * TM * 64;    // 16384
    constexpr int BBYT = 2 * TN * 64;    // 20480
    constexpr int BUFB = ABYT + BBYT;    // 36864
    constexpr int NREG = BUFB / 1024;    // 36
    constexpr int RPW = NREG / WAVES;    // 9
    constexpr int NWG = NBM * NBN;
    static_assert(NWG % 8 == 0 && NBM % 8 == 0, "grid must chunk by 8");

    __shared__ __align__(16) char LDSB[2 * BUFB];   // 72 KiB dbuf

    // ---- XCD-chunked + group-raster block mapping ----
    const int orig = blockIdx.x;
    const int lid = (orig & 7) * (NWG >> 3) + (orig >> 3);   // XCD-contiguous
    constexpr int BAND = 8 * NBN;
    const int band = lid / BAND;
    const int rem = lid - band * BAND;
    const int bn = rem >> 3;
    const int bm = (band << 3) + (rem & 7);

    const int tid = threadIdx.x;
    const int lane = tid & 63, wv = tid >> 6;
    const int wm = wv >> 1, wn = wv & 1;
    const int col = lane & 15, grp = lane >> 4;

    // staging descriptors (hoisted). Region = 16 rows x 64B. Lane l -> row l>>2,
    // LDS chunk-pos l&3; fetch global chunk (l&3) ^ ((row>>1)&3) = (l&3)^((l>>3)&3).
    const _Float16* srcp[RPW];
    int ldsoff[RPW];
    const int swz = ((lane & 3) ^ ((lane >> 3) & 3)) << 3;   // f16 elems
#pragma unroll
    for (int i = 0; i < RPW; ++i) {
        int r = wv + i * WAVES;          // 0..35
        bool isB = r >= 16;
        int rr = isB ? r - 16 : r;
        int rpp = isB ? 10 : 8;
        int plane = rr / rpp;
        int rip = (rr - plane * rpp) * 16 + (lane >> 2);
        const _Float16* base = isB ? (plane ? Bl : Bh) : (plane ? Al : Ah);
        int grow = (isB ? bn * TN : bm * TM) + rip;
        srcp[i] = base + (((size_t)grow) << 10) + swz;
        ldsoff[i] = r * 1024;
    }

    f32x4 acc[MF][NF];
#pragma unroll
    for (int i = 0; i < MF; ++i)
#pragma unroll
        for (int j = 0; j < NF; ++j) acc[i][j] = (f32x4)0.f;

    // prologue: stage chunk 0 into buf0
#pragma unroll
    for (int i = 0; i < RPW; ++i) gload_lds16(srcp[i], LDSB + ldsoff[i]);
    __syncthreads();

    for (int c = 0; c < NCH; ++c) {
        const int cb = c & 1;
        if (c + 1 < NCH) {
            const int nbuf = cb ^ 1;
#pragma unroll
            for (int i = 0; i < RPW; ++i)
                gload_lds16(srcp[i] + (c + 1) * KCH, LDSB + nbuf * BUFB + ldsoff[i]);
        }
        const char* LA  = LDSB + cb * BUFB;
        const char* LAl = LA + TM * 64;
        const char* LB  = LA + ABYT;
        const char* LBl = LB + TN * 64;

        half8 bh[NF], bl_[NF];
#pragma unroll
        for (int fn = 0; fn < NF; ++fn) {
            int row = wn * WNS + fn * 16 + col;
            int j = (grp ^ ((row >> 1) & 3)) << 4;
            bh[fn]  = *(const half8*)(LB  + row * 64 + j);
            bl_[fn] = *(const half8*)(LBl + row * 64 + j);
        }
        __builtin_amdgcn_s_setprio(1);
#pragma unroll
        for (int fm = 0; fm < MF; ++fm) {
            int row = wm * WMS + fm * 16 + col;
            int j = (grp ^ ((row >> 1) & 3)) << 4;
            half8 ah  = *(const half8*)(LA  + row * 64 + j);
            half8 al_ = *(const half8*)(LAl + row * 64 + j);
#pragma unroll
            for (int fn = 0; fn < NF; ++fn) {
                acc[fm][fn] = __builtin_amdgcn_mfma_f32_16x16x32_f16(ah,  bh[fn],  acc[fm][fn], 0, 0, 0);
                acc[fm][fn] = __builtin_amdgcn_mfma_f32_16x16x32_f16(ah,  bl_[fn], acc[fm][fn], 0, 0, 0);
                acc[fm][fn] = __builtin_amdgcn_mfma_f32_16x16x32_f16(al_, bh[fn],  acc[fm][fn], 0, 0, 0);
            }
        }
        __builtin_amdgcn_s_setprio(0);
        __syncthreads();
    }

    // epilogue: per-4row-chunk col max into LDS (padded stride), then group-slice
    // maxes -> global atomicMax (order-preserving encoding).
    float* cm = (float*)LDSB;            // [TM/4][TN+1]
    constexpr int CMS = TN + 1;
#pragma unroll
    for (int fm = 0; fm < MF; ++fm) {
        int rc = ((wm * WMS + fm * 16) >> 2) + grp;
#pragma unroll
        for (int fn = 0; fn < NF; ++fn) {
            f32x4 v = acc[fm][fn];
            float m = fmaxf(fmaxf(v[0], v[1]), fmaxf(v[2], v[3]));
            cm[rc * CMS + wn * WNS + fn * 16 + col] = m;
        }
    }
    __syncthreads();
    const int mrow0 = bm * TM;
    const int g0 = mrow0 / G;
    const int g1 = (mrow0 + TM - 1) / G;
    const int ngs = g1 - g0 + 1;
    for (int it = tid; it < ngs * TN; it += THREADS) {
        int gi = it / TN, cc = it - gi * TN;
        int g = g0 + gi;
        int rs = g * G;        if (rs < mrow0) rs = mrow0;
        int re = (g + 1) * G;  if (re > mrow0 + TM) re = mrow0 + TM;
        float m = -INFINITY;
        int rc0 = (rs - mrow0) >> 2, rc1 = (re - mrow0) >> 2;
        for (int rc = rc0; rc < rc1; ++rc) m = fmaxf(m, cm[rc * CMS + cc]);
        atomicMax(&cmax[(size_t)g * Wc + bn * TN + cc], fenc(m));
    }
}

// ---------------- fused finish + top-3 (strict >, lowest index on ties) ----------------
template<int G2>
__global__ __launch_bounds__(256) void finish_topk_kernel(
    const unsigned int* __restrict__ cmax, int Wc,
    float* __restrict__ vals, int* __restrict__ outidx)
{
    __shared__ float sims[NB];
    int n = blockIdx.x, p = threadIdx.x;
    const unsigned int* row = cmax + (size_t)n * Wc + (size_t)p * G2;
    float s = 0.f;
#pragma unroll
    for (int l = 0; l < G2; ++l) s += fdec(row[l]);
    sims[p] = s;
    __syncthreads();
    if (p < 64) {
        int lane = p;
        float v0 = -INFINITY, v1 = -INFINITY, v2 = -INFINITY;
        int i0 = 0x7fffffff, i1 = 0x7fffffff, i2 = 0x7fffffff;
        for (int q = lane; q < NB; q += 64) {
            float v = sims[q];
            if (v > v0)      { v2 = v1; i2 = i1; v1 = v0; i1 = i0; v0 = v; i0 = q; }
            else if (v > v1) { v2 = v1; i2 = i1; v1 = v;  i1 = q; }
            else if (v > v2) { v2 = v;  i2 = q; }
        }
#pragma unroll
        for (int off = 32; off; off >>= 1) {
            float w0 = __shfl_down(v0, off), w1 = __shfl_down(v1, off), w2 = __shfl_down(v2, off);
            int   j0 = __shfl_down(i0, off), j1 = __shfl_down(i1, off), j2 = __shfl_down(i2, off);
#define INS3(w, j)                                                                   \
            if (w > v0 || (w == v0 && j < i0)) { v2=v1;i2=i1; v1=v0;i1=i0; v0=w;i0=j; }  \
            else if (w > v1 || (w == v1 && j < i1)) { v2=v1;i2=i1; v1=w;i1=j; }          \
            else if (w > v2 || (w == v2 && j < i2)) { v2=w;i2=j; }
            INS3(w0, j0); INS3(w1, j1); INS3(w2, j2);
#undef INS3
        }
        if (lane == 0) {
            vals[n * 3 + 0] = v0; vals[n * 3 + 1] = v1; vals[n * 3 + 2] = v2;
            outidx[n * 3 + 0] = i0; outidx[n * 3 + 1] = i1; outidx[n * 3 + 2] = i2;
        }
    }
}

// ---------------- stage-2: hi-plane MFMA block-sim, 1 wave per (n,k) ----------------
// out[t] = sum_{l<L} max_r ( Ah[n,r,:] . Bh[bsel[t],l,:] )  (f16 hi only; err ~1e-4)
template<int R, int L>
__global__ __launch_bounds__(64) void stage2_kernel(
    const _Float16* __restrict__ Ah, const _Float16* __restrict__ Bh,
    const int* __restrict__ bsel, float* __restrict__ m2k)
{
    constexpr int MF = (R + 15) / 16, NF = (L + 15) / 16;
    int t = blockIdx.x;              // NB*KSEL
    int n = t / KSEL;
    int b = bsel[t];
    const _Float16* Ab = Ah + (size_t)n * R * DD;
    const _Float16* Bb = Bh + (size_t)b * L * DD;
    int lane = threadIdx.x;
    int col = lane & 15, grp = lane >> 4;

    int ra[MF], lb[NF];
#pragma unroll
    for (int i = 0; i < MF; ++i) ra[i] = min(i * 16 + col, R - 1);  // dup rows: max-safe
#pragma unroll
    for (int j = 0; j < NF; ++j) lb[j] = min(j * 16 + col, L - 1);  // dup cols: masked in sum

    f32x4 acc[MF][NF];
#pragma unroll
    for (int i = 0; i < MF; ++i)
#pragma unroll
        for (int j = 0; j < NF; ++j) acc[i][j] = (f32x4)0.f;

    for (int c = 0; c < DD / 32; ++c) {
        int k0 = c * 32 + grp * 8;
        half8 af[MF], bf[NF];
#pragma unroll
        for (int i = 0; i < MF; ++i) af[i] = *(const half8*)(Ab + (size_t)ra[i] * DD + k0);
#pragma unroll
        for (int j = 0; j < NF; ++j) bf[j] = *(const half8*)(Bb + (size_t)lb[j] * DD + k0);
#pragma unroll
        for (int i = 0; i < MF; ++i)
#pragma unroll
            for (int j = 0; j < NF; ++j)
                acc[i][j] = __builtin_amdgcn_mfma_f32_16x16x32_f16(af[i], bf[j], acc[i][j], 0, 0, 0);
    }

    float s = 0.f;
#pragma unroll
    for (int j = 0; j < NF; ++j) {
        float m = -INFINITY;
#pragma unroll
        for (int i = 0; i < MF; ++i) {
#pragma unroll
            for (int r = 0; r < 4; ++r) m = fmaxf(m, acc[i][j][r]);
        }
        m = fmaxf(m, __shfl_xor(m, 16));
        m = fmaxf(m, __shfl_xor(m, 32));
        if (j * 16 + col < L) s += m;
    }
    s += __shfl_xor(s, 1);
    s += __shfl_xor(s, 2);
    s += __shfl_xor(s, 4);
    s += __shfl_xor(s, 8);
    if (lane == 0) m2k[t] = s;
}

// ---------------- KL(p || q) ----------------
__global__ void loss_kernel(const float* __restrict__ m1k, const float* __restrict__ m2k,
                            float* __restrict__ out) {
    int n = threadIdx.x;
    float a[3], b[3];
#pragma unroll
    for (int i = 0; i < 3; ++i) {
        a[i] = m1k[n * 3 + i] * (1.0f / TAU);
        b[i] = m2k[n * 3 + i] * (1.0f / TAU);
    }
    float am = fmaxf(a[0], fmaxf(a[1], a[2]));
    float bm = fmaxf(b[0], fmaxf(b[1], b[2]));
    float ase = expf(a[0] - am) + expf(a[1] - am) + expf(a[2] - am);
    float bse = expf(b[0] - bm) + expf(b[1] - bm) + expf(b[2] - bm);
    float alse = am + logf(ase);
    float blse = bm + logf(bse);
    float acc = 0.f;
#pragma unroll
    for (int i = 0; i < 3; ++i) {
        float lp = a[i] - alse, lq = b[i] - blse;
        acc += expf(lp) * (lp - lq);
    }
#pragma unroll
    for (int off = 32; off; off >>= 1) acc += __shfl_down(acc, off);
    __shared__ float w[4];
    if ((threadIdx.x & 63) == 0) w[threadIdx.x >> 6] = acc;
    __syncthreads();
    if (threadIdx.x == 0) atomicAdd(out, w[0] + w[1] + w[2] + w[3]);
}

extern "C" void kernel_launch(void* const* d_in, const int* in_sizes, int n_in,
                              void* d_out, int out_size, void* d_ws, size_t ws_size,
                              hipStream_t stream) {
    const float* img_n = (const float*)d_in[0];   // [256,36,1024]
    const float* cap_n = (const float*)d_in[1];   // [256,32,1024]
    const float* img_p = (const float*)d_in[2];   // [256,36,1024]
    const float* cap_p = (const float*)d_in[3];   // [256,32,1024]
    float* out = (float*)d_out;

    char* w = (char*)d_ws;
    auto alloc = [&](size_t bytes) -> char* {
        char* p = w;
        w += (bytes + 255) & ~(size_t)255;
        return p;
    };
    const size_t IMGE   = (size_t)NB * 36 * DD;   // 9216 rows (72 x 128 M-tiles exact)
    const size_t CAPE   = (size_t)NB * 32 * DD;   // 8192 rows (64 x 128 exact)
    const size_t IMGPE  = (size_t)9280 * DD;      // img_p padded to 58 x 160 N-tiles
    const size_t CAPPE  = (size_t)8320 * DD;      // cap_p padded to 52 x 160 N-tiles
    const int WC1 = 9280, WC2 = 8320;

    _Float16* imgN_h = (_Float16*)alloc(IMGE * 2);
    _Float16* imgN_l = (_Float16*)alloc(IMGE * 2);
    _Float16* imgP_h = (_Float16*)alloc(IMGPE * 2);
    _Float16* imgP_l = (_Float16*)alloc(IMGPE * 2);
    _Float16* capN_h = (_Float16*)alloc(CAPE * 2);
    _Float16* capN_l = (_Float16*)alloc(CAPE * 2);
    _Float16* capP_h = (_Float16*)alloc(CAPPE * 2);
    _Float16* capP_l = (_Float16*)alloc(CAPPE * 2);

    const size_t CM1 = (size_t)256 * WC1 * 4;
    const size_t CM2 = (size_t)256 * WC2 * 4;
    unsigned int* cmax1 = (unsigned int*)alloc(CM1);
    unsigned int* cmax2 = (unsigned int*)alloc(CM2);

    float* m1k1 = (float*)alloc(NB * 3 * 4);
    float* m2k1 = (float*)alloc(NB * 3 * 4);
    float* m1k2 = (float*)alloc(NB * 3 * 4);
    float* m2k2 = (float*)alloc(NB * 3 * 4);
    int* idx1 = (int*)alloc(NB * 3 * 4);
    int* idx2 = (int*)alloc(NB * 3 * 4);

    hipMemsetAsync(d_out, 0, sizeof(float), stream);
    hipMemsetAsync(cmax1, 0, CM1, stream);
    hipMemsetAsync(cmax2, 0, CM2, stream);
    // zero padded B-row tails (fake columns, never read by finish)
    hipMemsetAsync(imgP_h + IMGE, 0, (IMGPE - IMGE) * 2, stream);
    hipMemsetAsync(imgP_l + IMGE, 0, (IMGPE - IMGE) * 2, stream);
    hipMemsetAsync(capP_h + CAPE, 0, (CAPPE - CAPE) * 2, stream);
    hipMemsetAsync(capP_l + CAPE, 0, (CAPPE - CAPE) * 2, stream);

    norm_split_kernel<<<NB * 36, 256, 0, stream>>>(img_n, imgN_h, imgN_l);
    norm_split_kernel<<<NB * 36, 256, 0, stream>>>(img_p, imgP_h, imgP_l);
    norm_split_kernel<<<NB * 32, 256, 0, stream>>>(cap_n, capN_h, capN_l);
    norm_split_kernel<<<NB * 32, 256, 0, stream>>>(cap_p, capP_h, capP_l);

    // call 1: semantic_transfer_loss(img_n, img_p, cap_p) — 9216x9280, G=36
    mfma_simX_kernel<36, 72, 58><<<72 * 58, 256, 0, stream>>>(
        imgN_h, imgN_l, imgP_h, imgP_l, cmax1, WC1);
    finish_topk_kernel<36><<<NB, 256, 0, stream>>>(cmax1, WC1, m1k1, idx1);
    stage2_kernel<36, 32><<<NB * KSEL, 64, 0, stream>>>(imgN_h, capP_h, idx1, m2k1);
    loss_kernel<<<1, NB, 0, stream>>>(m1k1, m2k1, out);

    // call 2: semantic_transfer_loss(cap_n, cap_p, img_p) — 8192x8320, G=32
    mfma_simX_kernel<32, 64, 52><<<64 * 52, 256, 0, stream>>>(
        capN_h, capN_l, capP_h, capP_l, cmax2, WC2);
    finish_topk_kernel<32><<<NB, 256, 0, stream>>>(cmax2, WC2, m1k2, idx2);
    stage2_kernel<32, 36><<<NB * KSEL, 64, 0, stream>>>(capN_h, imgP_h, idx2, m2k2);
    loss_kernel<<<1, NB, 0, stream>>>(m1k2, m2k2, out);
}